// Round 4
// baseline (2737.940 us; speedup 1.0000x reference)
//
#include <hip/hip_runtime.h>
#include <hip/hip_bf16.h>

// ---------------- problem constants ----------------
// conv1: x[128,1,28,28] * w[256,1,9,9] stride1 -> h1[128,256,20,20]
// caps1: h1 * w[256,256,9,9] stride2 -> h2[128,256,6,6]
// u_hat (recomputed on the fly): [128,1152,10,16]; routing p=1152, q=10
// OUTPUT IS float32 (reference returns f32; checker casts ref to bf16 only).

// ---------------- ws layout (float offsets) ----------------
#define N_H1   (128*256*400)            // 13107200
#define N_H2   (128*256*36)             // 1179648
#define N_BIJ  (128*1152*10)            // 1474560, layout [b][p][q]
#define N_V    (128*10*16)              // 20480
#define OFF_H1  0
#define OFF_H2  (OFF_H1 + N_H1)
#define OFF_BIJ (OFF_H2 + N_H2)
#define OFF_V   (OFF_BIJ + N_BIJ)
// total ~63.1 MB

// ================= conv1 + relu =================
__global__ __launch_bounds__(256) void conv1_kernel(
    const float* __restrict__ x, const float* __restrict__ w,
    const float* __restrict__ bias, float* __restrict__ h1) {
  int blk = blockIdx.x;
  int b = blk >> 7;
  int co0 = (blk & 127) << 1;
  __shared__ __align__(16) float xs[784];
  __shared__ float wsm[162];
  int t = threadIdx.x;
  for (int l = t; l < 784; l += 256) xs[l] = x[b * 784 + l];
  if (t < 162) wsm[t] = w[co0 * 81 + t];
  __syncthreads();
  int co_l = t & 1, g = t >> 1;
  if (g < 100) {
    int oy = g / 5, gx = (g % 5) * 4;
    float bs = bias[co0 + co_l];
    float acc0 = bs, acc1 = bs, acc2 = bs, acc3 = bs;
    for (int ky = 0; ky < 9; ++ky) {
      const float* xrow = &xs[(oy + ky) * 28 + gx];
      float xr[12];
#pragma unroll
      for (int i = 0; i < 3; ++i) {
        float4 v4 = *reinterpret_cast<const float4*>(&xrow[i * 4]);
        xr[i * 4 + 0] = v4.x; xr[i * 4 + 1] = v4.y; xr[i * 4 + 2] = v4.z; xr[i * 4 + 3] = v4.w;
      }
      const float* wrow = &wsm[co_l * 81 + ky * 9];
#pragma unroll
      for (int kx = 0; kx < 9; ++kx) {
        float wv = wrow[kx];
        acc0 += wv * xr[kx + 0];
        acc1 += wv * xr[kx + 1];
        acc2 += wv * xr[kx + 2];
        acc3 += wv * xr[kx + 3];
      }
    }
    float4 o4;
    o4.x = fmaxf(acc0, 0.f); o4.y = fmaxf(acc1, 0.f);
    o4.z = fmaxf(acc2, 0.f); o4.w = fmaxf(acc3, 0.f);
    *reinterpret_cast<float4*>(&h1[(b * 256 + co0 + co_l) * 400 + oy * 20 + gx]) = o4;
  }
}

// ================= caps1 conv (stride2) + relu =================
__global__ __launch_bounds__(192) void caps1_kernel(
    const float* __restrict__ h1, const float* __restrict__ w,
    const float* __restrict__ bias, float* __restrict__ h2) {
  int bp = blockIdx.x >> 3;
  int b0 = bp << 1;
  int co0 = (blockIdx.x & 7) << 5;
  __shared__ __align__(16) float ins[2][400];
  __shared__ float wsm[2592];  // [32 co][81]
  int t = threadIdx.x;
  int co_l = t & 31;
  int row = t >> 5;  // 0..5
  float acc[2][6];
#pragma unroll
  for (int i = 0; i < 2; ++i)
#pragma unroll
    for (int j = 0; j < 6; ++j) acc[i][j] = 0.f;

  for (int ci = 0; ci < 256; ++ci) {
    __syncthreads();
    for (int l = t; l < 800; l += 192) {
      int b2 = l / 400, px = l - b2 * 400;
      ins[b2][px] = h1[((b0 + b2) * 256 + ci) * 400 + px];
    }
    for (int l = t; l < 2592; l += 192) {
      int cg = l / 81, k = l - cg * 81;
      wsm[l] = w[((co0 + cg) * 256 + ci) * 81 + k];
    }
    __syncthreads();
#pragma unroll
    for (int ky = 0; ky < 9; ++ky) {
      float wr[9];
#pragma unroll
      for (int kx = 0; kx < 9; ++kx) wr[kx] = wsm[co_l * 81 + ky * 9 + kx];
#pragma unroll
      for (int b2 = 0; b2 < 2; ++b2) {
        const float* xrow = &ins[b2][(2 * row + ky) * 20];
        float xr[20];
#pragma unroll
        for (int i = 0; i < 5; ++i) {
          float4 v4 = *reinterpret_cast<const float4*>(&xrow[i * 4]);
          xr[i * 4 + 0] = v4.x; xr[i * 4 + 1] = v4.y; xr[i * 4 + 2] = v4.z; xr[i * 4 + 3] = v4.w;
        }
#pragma unroll
        for (int ox = 0; ox < 6; ++ox)
#pragma unroll
          for (int kx = 0; kx < 9; ++kx)
            acc[b2][ox] += wr[kx] * xr[2 * ox + kx];
      }
    }
  }
  float bs = bias[co0 + co_l];
#pragma unroll
  for (int b2 = 0; b2 < 2; ++b2)
#pragma unroll
    for (int ox = 0; ox < 6; ++ox)
      h2[((b0 + b2) * 256 + co0 + co_l) * 36 + row * 6 + ox] = fmaxf(acc[b2][ox] + bs, 0.f);
}

// ================= on-the-fly u_hat[16] for one (b, pq) =================
// u_hat[m] = sum_n W[pq, m>>1, (m&1)*8+n] * xv[n]
// xv[n] = h2[b, f/360, f%36], f = pq*8+n   (pq = p*10+q)
__device__ __forceinline__ void compute_u16(
    const float* __restrict__ h2b,  // &h2[b*9216]
    const float* __restrict__ W, int pq, float* u) {
  float xv[8];
#pragma unroll
  for (int n = 0; n < 8; ++n) {
    int f = pq * 8 + n;
    int c = f / 360;
    int ij = f % 36;
    xv[n] = h2b[c * 36 + ij];
  }
#pragma unroll
  for (int a = 0; a < 8; ++a) {
    const float4* wrow = reinterpret_cast<const float4*>(&W[(pq * 8 + a) * 16]);
    float4 w0 = wrow[0], w1 = wrow[1], w2 = wrow[2], w3 = wrow[3];
    u[2 * a] = w0.x * xv[0] + w0.y * xv[1] + w0.z * xv[2] + w0.w * xv[3]
             + w1.x * xv[4] + w1.y * xv[5] + w1.z * xv[6] + w1.w * xv[7];
    u[2 * a + 1] = w2.x * xv[0] + w2.y * xv[1] + w2.z * xv[2] + w2.w * xv[3]
                 + w3.x * xv[4] + w3.y * xv[5] + w3.z * xv[6] + w3.w * xv[7];
  }
}

// ================= routing: softmax + weighted sum + squash =================
// grid = b*10+q (1280 blocks), 256 threads. bij layout [b][p][q].
template <bool FINAL>
__global__ __launch_bounds__(256) void sv_kernel(
    const float* __restrict__ h2, const float* __restrict__ W,
    const float* __restrict__ bij, const float* __restrict__ caps_bias,
    float* __restrict__ v, float* __restrict__ out) {
  int b = blockIdx.x / 10, q = blockIdx.x % 10;
  int t = threadIdx.x;
  const float* h2b = &h2[b * 9216];
  const float* bijb = &bij[(size_t)b * 11520];
  float s[16];
#pragma unroll
  for (int m = 0; m < 16; ++m) s[m] = 0.f;
  for (int p = t; p < 1152; p += 256) {
    float bv[10], mx = -1e30f;
#pragma unroll
    for (int qq = 0; qq < 10; ++qq) {
      bv[qq] = bijb[p * 10 + qq];
      mx = fmaxf(mx, bv[qq]);
    }
    float den = 0.f;
#pragma unroll
    for (int qq = 0; qq < 10; ++qq) den += __expf(bv[qq] - mx);
    float c = __expf(bv[q] - mx) / den;
    float u[16];
    compute_u16(h2b, W, p * 10 + q, u);
#pragma unroll
    for (int m = 0; m < 16; ++m) s[m] += c * u[m];
  }
  __shared__ float red[4][16];
#pragma unroll
  for (int m = 0; m < 16; ++m) {
    float val = s[m];
    for (int off = 32; off > 0; off >>= 1) val += __shfl_down(val, off);
    if ((t & 63) == 0) red[t >> 6][m] = val;
  }
  __syncthreads();
  if (t == 0) {
    float sv[16];
    float sq = 0.f;
#pragma unroll
    for (int m = 0; m < 16; ++m) {
      float tot = red[0][m] + red[1][m] + red[2][m] + red[3][m] + caps_bias[q * 16 + m];
      sv[m] = tot;
      sq += tot * tot;
    }
    float coef = (sq / (1.f + sq)) * rsqrtf(sq + 1e-9f);
    float vl2 = 0.f;
#pragma unroll
    for (int m = 0; m < 16; ++m) {
      float vv = coef * sv[m];
      v[(b * 10 + q) * 16 + m] = vv;
      vl2 += vv * vv;
    }
    if (FINAL) out[b * 10 + q] = sqrtf(vl2 + 1e-9f);
  }
}

// ================= agreement update =================
// grid 5760 x 256; tid = b*11520 + pq (pq fastest -> coalesced W/bij)
__global__ __launch_bounds__(256) void agree_kernel(
    const float* __restrict__ h2, const float* __restrict__ W,
    const float* __restrict__ v, float* __restrict__ bij) {
  int tid = blockIdx.x * 256 + threadIdx.x;
  int b = tid / 11520;
  int pq = tid - b * 11520;
  int q = pq % 10;
  float u[16];
  compute_u16(&h2[b * 9216], W, pq, u);
  const float4* v4 = reinterpret_cast<const float4*>(&v[(b * 10 + q) * 16]);
  float4 b0 = v4[0], b1 = v4[1], b2 = v4[2], b3 = v4[3];
  float d = u[0] * b0.x + u[1] * b0.y + u[2] * b0.z + u[3] * b0.w
          + u[4] * b1.x + u[5] * b1.y + u[6] * b1.z + u[7] * b1.w
          + u[8] * b2.x + u[9] * b2.y + u[10] * b2.z + u[11] * b2.w
          + u[12] * b3.x + u[13] * b3.y + u[14] * b3.z + u[15] * b3.w;
  bij[(size_t)b * 11520 + pq] += d;
}

// ================= masked_v + fc1 + fc2 + fc3 + sigmoid =================
// grid = 128 (one block per b), 256 threads
__global__ __launch_bounds__(256) void fc_kernel(
    const float* __restrict__ v, const float* __restrict__ y,
    const float* __restrict__ fc1_w, const float* __restrict__ fc1_b,
    const float* __restrict__ fc2_w, const float* __restrict__ fc2_b,
    const float* __restrict__ fc3_w, const float* __restrict__ fc3_b,
    float* __restrict__ out) {
  int b = blockIdx.x;
  int t = threadIdx.x;
  __shared__ float mv[16];
  __shared__ float f1[512];
  __shared__ float f2[1024];
  if (t < 16) {
    // masked_v[u] = sum_t v_flat[b, u*10+t] * y[b,t]  (reshape semantics)
    const float* vb = &v[b * 160];
    float a = 0.f;
#pragma unroll
    for (int tt = 0; tt < 10; ++tt) a += vb[t * 10 + tt] * y[b * 10 + tt];
    mv[t] = a;
  }
  __syncthreads();
  for (int o = t; o < 512; o += 256) {
    const float4* wr = reinterpret_cast<const float4*>(&fc1_w[o * 16]);
    float4 w0 = wr[0], w1 = wr[1], w2 = wr[2], w3 = wr[3];
    float a = fc1_b[o]
        + mv[0] * w0.x + mv[1] * w0.y + mv[2] * w0.z + mv[3] * w0.w
        + mv[4] * w1.x + mv[5] * w1.y + mv[6] * w1.z + mv[7] * w1.w
        + mv[8] * w2.x + mv[9] * w2.y + mv[10] * w2.z + mv[11] * w2.w
        + mv[12] * w3.x + mv[13] * w3.y + mv[14] * w3.z + mv[15] * w3.w;
    f1[o] = a;
  }
  __syncthreads();
  for (int o = t; o < 1024; o += 256) {
    const float4* wr = reinterpret_cast<const float4*>(&fc2_w[o * 512]);
    float a = fc2_b[o];
#pragma unroll 4
    for (int k4 = 0; k4 < 128; ++k4) {
      float4 w4 = wr[k4];
      a += f1[4 * k4 + 0] * w4.x + f1[4 * k4 + 1] * w4.y
         + f1[4 * k4 + 2] * w4.z + f1[4 * k4 + 3] * w4.w;
    }
    f2[o] = a;
  }
  __syncthreads();
  for (int o = t; o < 784; o += 256) {
    const float4* wr = reinterpret_cast<const float4*>(&fc3_w[o * 1024]);
    float a = fc3_b[o];
#pragma unroll 4
    for (int k4 = 0; k4 < 256; ++k4) {
      float4 w4 = wr[k4];
      a += f2[4 * k4 + 0] * w4.x + f2[4 * k4 + 1] * w4.y
         + f2[4 * k4 + 2] * w4.z + f2[4 * k4 + 3] * w4.w;
    }
    float sig = 1.f / (1.f + __expf(-a));
    out[1280 + b * 784 + o] = sig;
  }
}

extern "C" void kernel_launch(void* const* d_in, const int* in_sizes, int n_in,
                              void* d_out, int out_size, void* d_ws, size_t ws_size,
                              hipStream_t stream) {
  const float* x       = (const float*)d_in[0];
  const float* y       = (const float*)d_in[1];
  const float* conv1_w = (const float*)d_in[2];
  const float* conv1_b = (const float*)d_in[3];
  const float* caps1_w = (const float*)d_in[4];
  const float* caps1_b = (const float*)d_in[5];
  const float* W       = (const float*)d_in[6];
  const float* cbias   = (const float*)d_in[7];
  const float* fc1_w   = (const float*)d_in[8];
  const float* fc1_b   = (const float*)d_in[9];
  const float* fc2_w   = (const float*)d_in[10];
  const float* fc2_b   = (const float*)d_in[11];
  const float* fc3_w   = (const float*)d_in[12];
  const float* fc3_b   = (const float*)d_in[13];
  float* out = (float*)d_out;   // reference returns float32

  float* ws  = (float*)d_ws;
  float* h1  = ws + OFF_H1;
  float* h2  = ws + OFF_H2;
  float* bij = ws + OFF_BIJ;
  float* v   = ws + OFF_V;

  (void)hipMemsetAsync(bij, 0, (size_t)N_BIJ * sizeof(float), stream);

  conv1_kernel<<<128 * 128, 256, 0, stream>>>(x, conv1_w, conv1_b, h1);
  caps1_kernel<<<512, 192, 0, stream>>>(h1, caps1_w, caps1_b, h2);

  sv_kernel<false><<<1280, 256, 0, stream>>>(h2, W, bij, cbias, v, out);
  agree_kernel<<<5760, 256, 0, stream>>>(h2, W, v, bij);
  sv_kernel<false><<<1280, 256, 0, stream>>>(h2, W, bij, cbias, v, out);
  agree_kernel<<<5760, 256, 0, stream>>>(h2, W, v, bij);
  sv_kernel<true><<<1280, 256, 0, stream>>>(h2, W, bij, cbias, v, out);

  fc_kernel<<<128, 256, 0, stream>>>(v, y, fc1_w, fc1_b, fc2_w, fc2_b,
                                     fc3_w, fc3_b, out);
}

// Round 5
// 1122.639 us; speedup vs baseline: 2.4388x; 2.4388x over previous
//
#include <hip/hip_runtime.h>
#include <hip/hip_bf16.h>

typedef unsigned short ushort_t;
typedef __attribute__((ext_vector_type(8))) short short8;
typedef __attribute__((ext_vector_type(4))) float f32x4;

// ---------------- problem constants ----------------
// conv1: x[128,1,28,28]*w[256,1,9,9] s1 -> h1t[128,20,20,256] (NHWC bf16)
// caps1: implicit GEMM M=4608(b,pos) N=256(co) K=81*256 -> h2[128,256,36] f32
// routing p=1152, q=10 (u_hat recomputed on the fly); output f32.

// ---------------- ws layout (bytes) ----------------
#define OFFB_H1T  0u                       // 13107200 bf16 = 26214400 B
#define OFFB_WT   26214400u                // 5308416 bf16  = 10616832 B
#define OFFB_H2   36831232u                // 1179648 f32   =  4718592 B
#define OFFB_BIJ  41549824u                // 1474560 f32   =  5898240 B
#define OFFB_V    47448064u                // 20480 f32
// total ~47.5 MB

#define N_BIJ  (128*1152*10)

__device__ __forceinline__ ushort_t f2bf(float f) {
  union { float f; unsigned int u; } c; c.f = f;
  unsigned int r = (c.u + 0x7FFFu + ((c.u >> 16) & 1u)) >> 16;
  return (ushort_t)r;
}

// ================= conv1 + relu -> NHWC bf16 =================
// grid: b(128) x co-pair(128), block 256.
__global__ __launch_bounds__(256) void conv1_kernel(
    const float* __restrict__ x, const float* __restrict__ w,
    const float* __restrict__ bias, ushort_t* __restrict__ h1t) {
  int blk = blockIdx.x;
  int b = blk >> 7;
  int co0 = (blk & 127) << 1;
  __shared__ __align__(16) float xs[784];
  __shared__ float wsm[162];
  int t = threadIdx.x;
  for (int l = t; l < 784; l += 256) xs[l] = x[b * 784 + l];
  if (t < 162) wsm[t] = w[co0 * 81 + t];
  __syncthreads();
  int co_l = t & 1, g = t >> 1;
  if (g < 100) {
    int oy = g / 5, gx = (g % 5) * 4;
    float bs = bias[co0 + co_l];
    float acc[4] = {bs, bs, bs, bs};
    for (int ky = 0; ky < 9; ++ky) {
      const float* xrow = &xs[(oy + ky) * 28 + gx];
      float xr[12];
#pragma unroll
      for (int i = 0; i < 3; ++i) {
        float4 v4 = *reinterpret_cast<const float4*>(&xrow[i * 4]);
        xr[i * 4 + 0] = v4.x; xr[i * 4 + 1] = v4.y; xr[i * 4 + 2] = v4.z; xr[i * 4 + 3] = v4.w;
      }
      const float* wrow = &wsm[co_l * 81 + ky * 9];
#pragma unroll
      for (int kx = 0; kx < 9; ++kx) {
        float wv = wrow[kx];
#pragma unroll
        for (int i = 0; i < 4; ++i) acc[i] += wv * xr[kx + i];
      }
    }
    int xb = (b * 20 + oy) * 20 + gx;
#pragma unroll
    for (int i = 0; i < 4; ++i)
      h1t[(xb + i) * 256 + co0 + co_l] = f2bf(fmaxf(acc[i], 0.f));
  }
}

// ================= weight reorder: w[co][ci][kk] -> wt[kk][co][ci] bf16 ====
__global__ __launch_bounds__(256) void wreorder_kernel(
    const float* __restrict__ w, ushort_t* __restrict__ wt) {
  int co = blockIdx.x;
  int ci = threadIdx.x;
  const float* src = w + (co * 256 + ci) * 81;
  for (int kk = 0; kk < 81; ++kk)
    wt[(kk * 256 + co) * 256 + ci] = f2bf(src[kk]);
}

// ================= caps1 implicit GEMM (bf16 MFMA) =================
// M=4608 (m=b*36+pos), N=256 (co), K=81*256.  BM=BN=64, 4 waves of 32x32.
// K-step: (kk, ci0): A row = h1t[b][2oy+ky][2ox+kx][ci0..+63]
//                    B row = wt[kk][co][ci0..+63]
__global__ __launch_bounds__(256) void caps1_gemm(
    const ushort_t* __restrict__ h1t, const ushort_t* __restrict__ wt,
    const float* __restrict__ bias, float* __restrict__ h2) {
  int blk = blockIdx.x;          // 288 = 72 mi x 4 ni (ni fastest)
  int gm0 = (blk >> 2) * 64;
  int gn0 = (blk & 3) * 64;
  int t = threadIdx.x;
  int wave = t >> 6, lane = t & 63;
  int wm = (wave >> 1) * 32, wn = (wave & 1) * 32;
  int lr = lane & 15, lg = lane >> 4;

  __shared__ __align__(16) ushort_t As[2][64 * 72];  // +8 elem pad per row
  __shared__ __align__(16) ushort_t Bs[2][64 * 72];

  // staging coords: thread -> (row r, 16-elem segment seg)
  int r = t >> 2, seg = t & 3;
  int m = gm0 + r;
  int b = m / 36, pos = m % 36;
  int oy = pos / 6, ox = pos % 6;
  const ushort_t* arow = h1t + ((b * 20 + 2 * oy) * 20 + 2 * ox) * 256 + seg * 16;
  const ushort_t* brow = wt + (gn0 + r) * 256 + seg * 16;
  int lds_off = r * 72 + seg * 16;

  f32x4 acc[2][2];
#pragma unroll
  for (int i = 0; i < 2; ++i)
#pragma unroll
    for (int j = 0; j < 2; ++j)
#pragma unroll
      for (int e = 0; e < 4; ++e) acc[i][j][e] = 0.f;

  float4 ra0, ra1, rb0, rb1;
  // prologue: stage k-step 0 (kk=0 -> ky=0,kx=0, ci0=0)
  ra0 = *(const float4*)(arow);
  ra1 = *(const float4*)(arow + 8);
  rb0 = *(const float4*)(brow);
  rb1 = *(const float4*)(brow + 8);
  *(float4*)&As[0][lds_off] = ra0;
  *(float4*)&As[0][lds_off + 8] = ra1;
  *(float4*)&Bs[0][lds_off] = rb0;
  *(float4*)&Bs[0][lds_off + 8] = rb1;
  __syncthreads();

  int buf = 0;
  for (int ks = 0; ks < 324; ++ks) {
    int nxt = ks + 1;
    if (nxt < 324) {
      int kk = nxt >> 2, ci0 = (nxt & 3) << 6;
      int ky = kk / 9, kx = kk - ky * 9;
      const ushort_t* ap = arow + (ky * 20 + kx) * 256 + ci0;
      ra0 = *(const float4*)(ap);
      ra1 = *(const float4*)(ap + 8);
      const ushort_t* bp = brow + kk * 65536 + ci0;
      rb0 = *(const float4*)(bp);
      rb1 = *(const float4*)(bp + 8);
    }
    // compute on As[buf]/Bs[buf]
    short8 af[2][2], bfr[2][2];
#pragma unroll
    for (int kh = 0; kh < 2; ++kh) {
#pragma unroll
      for (int mf = 0; mf < 2; ++mf)
        af[mf][kh] = *(const short8*)&As[buf][(wm + mf * 16 + lr) * 72 + kh * 32 + lg * 8];
#pragma unroll
      for (int nf = 0; nf < 2; ++nf)
        bfr[nf][kh] = *(const short8*)&Bs[buf][(wn + nf * 16 + lr) * 72 + kh * 32 + lg * 8];
    }
#pragma unroll
    for (int kh = 0; kh < 2; ++kh)
#pragma unroll
      for (int mf = 0; mf < 2; ++mf)
#pragma unroll
        for (int nf = 0; nf < 2; ++nf)
          acc[mf][nf] = __builtin_amdgcn_mfma_f32_16x16x32_bf16(
              af[mf][kh], bfr[nf][kh], acc[mf][nf], 0, 0, 0);
    __syncthreads();
    if (nxt < 324) {
      int nb = buf ^ 1;
      *(float4*)&As[nb][lds_off] = ra0;
      *(float4*)&As[nb][lds_off + 8] = ra1;
      *(float4*)&Bs[nb][lds_off] = rb0;
      *(float4*)&Bs[nb][lds_off + 8] = rb1;
      __syncthreads();
    }
    buf ^= 1;
  }

  // epilogue: C[row=(lg*4+reg within 16-frag)][col=lr] ; bias + relu
#pragma unroll
  for (int mf = 0; mf < 2; ++mf) {
#pragma unroll
    for (int nf = 0; nf < 2; ++nf) {
      int nn = gn0 + wn + nf * 16 + lr;
      float bs = bias[nn];
#pragma unroll
      for (int reg = 0; reg < 4; ++reg) {
        int mm = gm0 + wm + mf * 16 + lg * 4 + reg;
        int bb = mm / 36, pp = mm - bb * 36;
        h2[(bb * 256 + nn) * 36 + pp] = fmaxf(acc[mf][nf][reg] + bs, 0.f);
      }
    }
  }
}

// ================= on-the-fly u_hat[16] =================
__device__ __forceinline__ void compute_u16(
    const float* __restrict__ h2b, const float* __restrict__ W, int pq,
    float* u) {
  float xv[8];
#pragma unroll
  for (int n = 0; n < 8; ++n) {
    int f = pq * 8 + n;
    int c = f / 360;
    int ij = f % 36;
    xv[n] = h2b[c * 36 + ij];
  }
#pragma unroll
  for (int a = 0; a < 8; ++a) {
    const float4* wrow = reinterpret_cast<const float4*>(&W[(pq * 8 + a) * 16]);
    float4 w0 = wrow[0], w1 = wrow[1], w2 = wrow[2], w3 = wrow[3];
    u[2 * a] = w0.x * xv[0] + w0.y * xv[1] + w0.z * xv[2] + w0.w * xv[3]
             + w1.x * xv[4] + w1.y * xv[5] + w1.z * xv[6] + w1.w * xv[7];
    u[2 * a + 1] = w2.x * xv[0] + w2.y * xv[1] + w2.z * xv[2] + w2.w * xv[3]
                 + w3.x * xv[4] + w3.y * xv[5] + w3.z * xv[6] + w3.w * xv[7];
  }
}

// ================= routing: softmax + weighted sum + squash =================
template <bool FINAL>
__global__ __launch_bounds__(256) void sv_kernel(
    const float* __restrict__ h2, const float* __restrict__ W,
    const float* __restrict__ bij, const float* __restrict__ caps_bias,
    float* __restrict__ v, float* __restrict__ out) {
  int b = blockIdx.x / 10, q = blockIdx.x % 10;
  int t = threadIdx.x;
  const float* h2b = &h2[b * 9216];
  const float* bijb = &bij[(size_t)b * 11520];
  float s[16];
#pragma unroll
  for (int m = 0; m < 16; ++m) s[m] = 0.f;
  for (int p = t; p < 1152; p += 256) {
    float bv[10], mx = -1e30f;
#pragma unroll
    for (int qq = 0; qq < 10; ++qq) {
      bv[qq] = bijb[p * 10 + qq];
      mx = fmaxf(mx, bv[qq]);
    }
    float den = 0.f;
#pragma unroll
    for (int qq = 0; qq < 10; ++qq) den += __expf(bv[qq] - mx);
    float c = __expf(bv[q] - mx) / den;
    float u[16];
    compute_u16(h2b, W, p * 10 + q, u);
#pragma unroll
    for (int m = 0; m < 16; ++m) s[m] += c * u[m];
  }
  __shared__ float red[4][16];
#pragma unroll
  for (int m = 0; m < 16; ++m) {
    float val = s[m];
    for (int off = 32; off > 0; off >>= 1) val += __shfl_down(val, off);
    if ((t & 63) == 0) red[t >> 6][m] = val;
  }
  __syncthreads();
  if (t == 0) {
    float sv[16];
    float sq = 0.f;
#pragma unroll
    for (int m = 0; m < 16; ++m) {
      float tot = red[0][m] + red[1][m] + red[2][m] + red[3][m] + caps_bias[q * 16 + m];
      sv[m] = tot;
      sq += tot * tot;
    }
    float coef = (sq / (1.f + sq)) * rsqrtf(sq + 1e-9f);
    float vl2 = 0.f;
#pragma unroll
    for (int m = 0; m < 16; ++m) {
      float vv = coef * sv[m];
      v[(b * 10 + q) * 16 + m] = vv;
      vl2 += vv * vv;
    }
    if (FINAL) out[b * 10 + q] = sqrtf(vl2 + 1e-9f);
  }
}

// ================= agreement update =================
__global__ __launch_bounds__(256) void agree_kernel(
    const float* __restrict__ h2, const float* __restrict__ W,
    const float* __restrict__ v, float* __restrict__ bij) {
  int tid = blockIdx.x * 256 + threadIdx.x;
  int b = tid / 11520;
  int pq = tid - b * 11520;
  int q = pq % 10;
  float u[16];
  compute_u16(&h2[b * 9216], W, pq, u);
  const float4* v4 = reinterpret_cast<const float4*>(&v[(b * 10 + q) * 16]);
  float4 b0 = v4[0], b1 = v4[1], b2 = v4[2], b3 = v4[3];
  float d = u[0] * b0.x + u[1] * b0.y + u[2] * b0.z + u[3] * b0.w
          + u[4] * b1.x + u[5] * b1.y + u[6] * b1.z + u[7] * b1.w
          + u[8] * b2.x + u[9] * b2.y + u[10] * b2.z + u[11] * b2.w
          + u[12] * b3.x + u[13] * b3.y + u[14] * b3.z + u[15] * b3.w;
  bij[(size_t)b * 11520 + pq] += d;
}

// ================= masked_v + fc1 + fc2 + fc3 + sigmoid =================
__global__ __launch_bounds__(256) void fc_kernel(
    const float* __restrict__ v, const float* __restrict__ y,
    const float* __restrict__ fc1_w, const float* __restrict__ fc1_b,
    const float* __restrict__ fc2_w, const float* __restrict__ fc2_b,
    const float* __restrict__ fc3_w, const float* __restrict__ fc3_b,
    float* __restrict__ out) {
  int b = blockIdx.x;
  int t = threadIdx.x;
  __shared__ float mv[16];
  __shared__ float f1[512];
  __shared__ float f2[1024];
  if (t < 16) {
    const float* vb = &v[b * 160];
    float a = 0.f;
#pragma unroll
    for (int tt = 0; tt < 10; ++tt) a += vb[t * 10 + tt] * y[b * 10 + tt];
    mv[t] = a;
  }
  __syncthreads();
  for (int o = t; o < 512; o += 256) {
    const float4* wr = reinterpret_cast<const float4*>(&fc1_w[o * 16]);
    float4 w0 = wr[0], w1 = wr[1], w2 = wr[2], w3 = wr[3];
    float a = fc1_b[o]
        + mv[0] * w0.x + mv[1] * w0.y + mv[2] * w0.z + mv[3] * w0.w
        + mv[4] * w1.x + mv[5] * w1.y + mv[6] * w1.z + mv[7] * w1.w
        + mv[8] * w2.x + mv[9] * w2.y + mv[10] * w2.z + mv[11] * w2.w
        + mv[12] * w3.x + mv[13] * w3.y + mv[14] * w3.z + mv[15] * w3.w;
    f1[o] = a;
  }
  __syncthreads();
  for (int o = t; o < 1024; o += 256) {
    const float4* wr = reinterpret_cast<const float4*>(&fc2_w[o * 512]);
    float a = fc2_b[o];
#pragma unroll 4
    for (int k4 = 0; k4 < 128; ++k4) {
      float4 w4 = wr[k4];
      a += f1[4 * k4 + 0] * w4.x + f1[4 * k4 + 1] * w4.y
         + f1[4 * k4 + 2] * w4.z + f1[4 * k4 + 3] * w4.w;
    }
    f2[o] = a;
  }
  __syncthreads();
  for (int o = t; o < 784; o += 256) {
    const float4* wr = reinterpret_cast<const float4*>(&fc3_w[o * 1024]);
    float a = fc3_b[o];
#pragma unroll 4
    for (int k4 = 0; k4 < 256; ++k4) {
      float4 w4 = wr[k4];
      a += f2[4 * k4 + 0] * w4.x + f2[4 * k4 + 1] * w4.y
         + f2[4 * k4 + 2] * w4.z + f2[4 * k4 + 3] * w4.w;
    }
    float sig = 1.f / (1.f + __expf(-a));
    out[1280 + b * 784 + o] = sig;
  }
}

extern "C" void kernel_launch(void* const* d_in, const int* in_sizes, int n_in,
                              void* d_out, int out_size, void* d_ws, size_t ws_size,
                              hipStream_t stream) {
  const float* x       = (const float*)d_in[0];
  const float* y       = (const float*)d_in[1];
  const float* conv1_w = (const float*)d_in[2];
  const float* conv1_b = (const float*)d_in[3];
  const float* caps1_w = (const float*)d_in[4];
  const float* caps1_b = (const float*)d_in[5];
  const float* W       = (const float*)d_in[6];
  const float* cbias   = (const float*)d_in[7];
  const float* fc1_w   = (const float*)d_in[8];
  const float* fc1_b   = (const float*)d_in[9];
  const float* fc2_w   = (const float*)d_in[10];
  const float* fc2_b   = (const float*)d_in[11];
  const float* fc3_w   = (const float*)d_in[12];
  const float* fc3_b   = (const float*)d_in[13];
  float* out = (float*)d_out;

  char* wsb = (char*)d_ws;
  ushort_t* h1t = (ushort_t*)(wsb + OFFB_H1T);
  ushort_t* wt  = (ushort_t*)(wsb + OFFB_WT);
  float* h2  = (float*)(wsb + OFFB_H2);
  float* bij = (float*)(wsb + OFFB_BIJ);
  float* v   = (float*)(wsb + OFFB_V);

  (void)hipMemsetAsync(bij, 0, (size_t)N_BIJ * sizeof(float), stream);

  conv1_kernel<<<128 * 128, 256, 0, stream>>>(x, conv1_w, conv1_b, h1t);
  wreorder_kernel<<<256, 256, 0, stream>>>(caps1_w, wt);
  caps1_gemm<<<288, 256, 0, stream>>>(h1t, wt, caps1_b, h2);

  sv_kernel<false><<<1280, 256, 0, stream>>>(h2, W, bij, cbias, v, out);
  agree_kernel<<<5760, 256, 0, stream>>>(h2, W, v, bij);
  sv_kernel<false><<<1280, 256, 0, stream>>>(h2, W, bij, cbias, v, out);
  agree_kernel<<<5760, 256, 0, stream>>>(h2, W, v, bij);
  sv_kernel<true><<<1280, 256, 0, stream>>>(h2, W, bij, cbias, v, out);

  fc_kernel<<<128, 256, 0, stream>>>(v, y, fc1_w, fc1_b, fc2_w, fc2_b,
                                     fc3_w, fc3_b, out);
}

// Round 6
// 428.056 us; speedup vs baseline: 6.3962x; 2.6226x over previous
//
#include <hip/hip_runtime.h>
#include <hip/hip_bf16.h>

typedef unsigned short ushort_t;
typedef __attribute__((ext_vector_type(8))) short short8;
typedef __attribute__((ext_vector_type(4))) float f32x4;

// ---------------- problem constants ----------------
// conv1: x[128,1,28,28]*w[256,1,9,9] s1 -> h1t[128,20,20,256] (NHWC bf16)
// caps1: implicit GEMM M=4608(b,pos) N=256(co) K=81*256, split-K x4
//        -> part[4][4608][256] f32 -> reduce -> h2[m=b*36+pos][n=co] f32
// u_hat: materialized bf16 [b][q][p][16]; routing p=1152, q=10; output f32.

// ---------------- ws layout (bytes); ws >= 157MB proven in r1/r2 ----------
#define OFFB_H1T  0u           // 26,214,400
#define OFFB_WT   26214400u    // 10,616,832
#define OFFB_PART 36831232u    // 18,874,368
#define OFFB_H2   55705600u    //  4,718,592
#define OFFB_UH   60424192u    // 47,185,920
#define OFFB_BIJ  107610112u   //  5,898,240
#define OFFB_C    113508352u   //  5,898,240
#define OFFB_V    119406592u   //     81,920
#define OFFB_F1   119488512u   //    262,144
#define OFFB_F2   119750656u   //    524,288  -> total 120.3 MB

__device__ __forceinline__ ushort_t f2bf(float f) {
  union { float f; unsigned int u; } c; c.f = f;
  unsigned int r = (c.u + 0x7FFFu + ((c.u >> 16) & 1u)) >> 16;
  return (ushort_t)r;
}
__device__ __forceinline__ float bf2f(ushort_t u) {
  union { unsigned int i; float f; } c; c.i = ((unsigned int)u) << 16;
  return c.f;
}

// ================= conv1 + relu -> NHWC bf16 =================
// grid = b*20+oy (2560), block 256 (t = co). 180 FMA per ky from registers.
__global__ __launch_bounds__(256) void conv1_kernel(
    const float* __restrict__ x, const float* __restrict__ w,
    const float* __restrict__ bias, ushort_t* __restrict__ h1t) {
  int blk = blockIdx.x;
  int b = blk / 20, oy = blk % 20;
  int co = threadIdx.x;
  __shared__ float xs[252];  // rows oy..oy+8, 28 cols
  for (int l = co; l < 252; l += 256)
    xs[l] = x[b * 784 + (oy + l / 28) * 28 + (l % 28)];
  __syncthreads();
  float bs = bias[co];
  float acc[20];
#pragma unroll
  for (int i = 0; i < 20; ++i) acc[i] = bs;
  for (int ky = 0; ky < 9; ++ky) {
    float xr[28];
#pragma unroll
    for (int i = 0; i < 28; ++i) xr[i] = xs[ky * 28 + i];
    float wk[9];
#pragma unroll
    for (int kx = 0; kx < 9; ++kx) wk[kx] = w[co * 81 + ky * 9 + kx];
#pragma unroll
    for (int kx = 0; kx < 9; ++kx)
#pragma unroll
      for (int ox = 0; ox < 20; ++ox) acc[ox] += wk[kx] * xr[ox + kx];
  }
  int xb = (b * 20 + oy) * 20;
#pragma unroll
  for (int ox = 0; ox < 20; ++ox)
    h1t[(xb + ox) * 256 + co] = f2bf(fmaxf(acc[ox], 0.f));
}

// ========== weight reorder: w[co][ci][kk] -> wt[kk][co][ci] bf16 ==========
__global__ __launch_bounds__(256) void wreorder_kernel(
    const float* __restrict__ w, ushort_t* __restrict__ wt) {
  int co = blockIdx.x;
  int ci = threadIdx.x;
  const float* src = w + (co * 256 + ci) * 81;
  for (int kk = 0; kk < 81; ++kk)
    wt[(kk * 256 + co) * 256 + ci] = f2bf(src[kk]);
}

// ================= caps1 implicit GEMM, split-K x4 =================
// grid 1152: chunk = blk/288, tile = blk%288 (72 mi x 4 ni, ni fastest).
__global__ __launch_bounds__(256) void caps1_gemm(
    const ushort_t* __restrict__ h1t, const ushort_t* __restrict__ wt,
    float* __restrict__ part) {
  int blk = blockIdx.x;
  int chunk = blk / 288;
  int tile = blk - chunk * 288;
  int gm0 = (tile >> 2) * 64;
  int gn0 = (tile & 3) * 64;
  int ks0 = chunk * 81, ks1 = ks0 + 81;
  int t = threadIdx.x;
  int wave = t >> 6, lane = t & 63;
  int wm = (wave >> 1) * 32, wn = (wave & 1) * 32;
  int lr = lane & 15, lg = lane >> 4;

  __shared__ __align__(16) ushort_t As[2][64 * 72];
  __shared__ __align__(16) ushort_t Bs[2][64 * 72];

  int r = t >> 2, seg = t & 3;
  int m = gm0 + r;
  int b = m / 36, pos = m - b * 36;
  int oy = pos / 6, ox = pos - oy * 6;
  const ushort_t* arow = h1t + ((b * 20 + 2 * oy) * 20 + 2 * ox) * 256 + seg * 16;
  const ushort_t* brow = wt + (gn0 + r) * 256 + seg * 16;
  int lds_off = r * 72 + seg * 16;

  f32x4 acc[2][2];
#pragma unroll
  for (int i = 0; i < 2; ++i)
#pragma unroll
    for (int j = 0; j < 2; ++j)
#pragma unroll
      for (int e = 0; e < 4; ++e) acc[i][j][e] = 0.f;

  float4 ra0, ra1, rb0, rb1;
  {
    int kk = ks0 >> 2, ci0 = (ks0 & 3) << 6;
    int ky = kk / 9, kx = kk - ky * 9;
    const ushort_t* ap = arow + (ky * 20 + kx) * 256 + ci0;
    ra0 = *(const float4*)(ap);
    ra1 = *(const float4*)(ap + 8);
    const ushort_t* bp = brow + kk * 65536 + ci0;
    rb0 = *(const float4*)(bp);
    rb1 = *(const float4*)(bp + 8);
  }
  *(float4*)&As[0][lds_off] = ra0;
  *(float4*)&As[0][lds_off + 8] = ra1;
  *(float4*)&Bs[0][lds_off] = rb0;
  *(float4*)&Bs[0][lds_off + 8] = rb1;
  __syncthreads();

  int buf = 0;
  for (int ks = ks0; ks < ks1; ++ks) {
    int nxt = ks + 1;
    if (nxt < ks1) {
      int kk = nxt >> 2, ci0 = (nxt & 3) << 6;
      int ky = kk / 9, kx = kk - ky * 9;
      const ushort_t* ap = arow + (ky * 20 + kx) * 256 + ci0;
      ra0 = *(const float4*)(ap);
      ra1 = *(const float4*)(ap + 8);
      const ushort_t* bp = brow + kk * 65536 + ci0;
      rb0 = *(const float4*)(bp);
      rb1 = *(const float4*)(bp + 8);
    }
    short8 af[2][2], bfr[2][2];
#pragma unroll
    for (int kh = 0; kh < 2; ++kh) {
#pragma unroll
      for (int mf = 0; mf < 2; ++mf)
        af[mf][kh] = *(const short8*)&As[buf][(wm + mf * 16 + lr) * 72 + kh * 32 + lg * 8];
#pragma unroll
      for (int nf = 0; nf < 2; ++nf)
        bfr[nf][kh] = *(const short8*)&Bs[buf][(wn + nf * 16 + lr) * 72 + kh * 32 + lg * 8];
    }
#pragma unroll
    for (int kh = 0; kh < 2; ++kh)
#pragma unroll
      for (int mf = 0; mf < 2; ++mf)
#pragma unroll
        for (int nf = 0; nf < 2; ++nf)
          acc[mf][nf] = __builtin_amdgcn_mfma_f32_16x16x32_bf16(
              af[mf][kh], bfr[nf][kh], acc[mf][nf], 0, 0, 0);
    __syncthreads();
    if (nxt < ks1) {
      int nb = buf ^ 1;
      *(float4*)&As[nb][lds_off] = ra0;
      *(float4*)&As[nb][lds_off + 8] = ra1;
      *(float4*)&Bs[nb][lds_off] = rb0;
      *(float4*)&Bs[nb][lds_off + 8] = rb1;
      __syncthreads();
    }
    buf ^= 1;
  }

  // partial write: part[(chunk*4608 + m)*256 + n]
#pragma unroll
  for (int mf = 0; mf < 2; ++mf)
#pragma unroll
    for (int nf = 0; nf < 2; ++nf) {
      int nn = gn0 + wn + nf * 16 + lr;
#pragma unroll
      for (int reg = 0; reg < 4; ++reg) {
        int mm = gm0 + wm + mf * 16 + lg * 4 + reg;
        part[((size_t)chunk * 4608 + mm) * 256 + nn] = acc[mf][nf][reg];
      }
    }
}

// ========= reduce: h2[m][n] = relu(sum_c part[c][m][n] + bias[n]) =========
__global__ __launch_bounds__(256) void reduce_kernel(
    const float* __restrict__ part, const float* __restrict__ bias,
    float* __restrict__ h2) {
  int m = blockIdx.x;
  int n = threadIdx.x;
  size_t o = (size_t)m * 256 + n;
  float s = part[o] + part[o + 4608 * 256] + part[o + 2 * 4608 * 256] +
            part[o + 3 * 4608 * 256];
  h2[o] = fmaxf(s + bias[n], 0.f);
}

// ================= u_hat materialize (bf16) =================
// tid = (b*10+q)*1152 + p; uh[((b*10+q)*1152+p)*16 + m]
// u[2a]   = sum_n W[pq,a,n]  *xv[n],  u[2a+1] = sum_n W[pq,a,8+n]*xv[n]
// xv[n] = h2[(b*36 + f%36)*256 + f/360], f = pq*8+n, pq = p*10+q
__global__ __launch_bounds__(256) void uhat_kernel(
    const float* __restrict__ h2, const float* __restrict__ W,
    ushort_t* __restrict__ uh) {
  int tid = blockIdx.x * 256 + threadIdx.x;
  int b = tid / 11520;
  int r1 = tid - b * 11520;
  int q = r1 / 1152;
  int p = r1 - q * 1152;
  int pq = p * 10 + q;
  const float* h2b = &h2[b * 9216];
  float xv[8];
#pragma unroll
  for (int n = 0; n < 8; ++n) {
    int f = pq * 8 + n;
    xv[n] = h2b[(f % 36) * 256 + (f / 360)];
  }
  short8 o0, o1;
#pragma unroll
  for (int a = 0; a < 8; ++a) {
    const float4* wrow = reinterpret_cast<const float4*>(&W[(pq * 8 + a) * 16]);
    float4 w0 = wrow[0], w1 = wrow[1], w2 = wrow[2], w3 = wrow[3];
    float ue = w0.x * xv[0] + w0.y * xv[1] + w0.z * xv[2] + w0.w * xv[3]
             + w1.x * xv[4] + w1.y * xv[5] + w1.z * xv[6] + w1.w * xv[7];
    float uo = w2.x * xv[0] + w2.y * xv[1] + w2.z * xv[2] + w2.w * xv[3]
             + w3.x * xv[4] + w3.y * xv[5] + w3.z * xv[6] + w3.w * xv[7];
    if (a < 4) { o0[2 * a] = (short)f2bf(ue); o0[2 * a + 1] = (short)f2bf(uo); }
    else { o1[2 * (a - 4)] = (short)f2bf(ue); o1[2 * (a - 4) + 1] = (short)f2bf(uo); }
  }
  *(short8*)&uh[(size_t)tid * 16] = o0;
  *(short8*)&uh[(size_t)tid * 16 + 8] = o1;
}

// ================= sv: weighted sum + squash =================
// MODE 0: c = 0.1 exactly (softmax of zeros); 1: read c; 2: read c + out.
// grid = b*10+q (1280), block 64 (one wave).
template <int MODE>
__global__ __launch_bounds__(64) void sv_kernel(
    const ushort_t* __restrict__ uh, const float* __restrict__ cbuf,
    const float* __restrict__ caps_bias, float* __restrict__ v,
    float* __restrict__ out) {
  int bq = blockIdx.x;
  int q = bq % 10;
  int t = threadIdx.x;
  const ushort_t* ub = &uh[(size_t)bq * 1152 * 16];
  const float* cb = &cbuf[(size_t)bq * 1152];
  float s[16];
#pragma unroll
  for (int m = 0; m < 16; ++m) s[m] = 0.f;
  for (int p = t; p < 1152; p += 64) {
    short8 u0 = *(const short8*)&ub[p * 16];
    short8 u1 = *(const short8*)&ub[p * 16 + 8];
    float c = (MODE == 0) ? 0.1f : cb[p];
#pragma unroll
    for (int m = 0; m < 8; ++m) s[m] += c * bf2f((ushort_t)u0[m]);
#pragma unroll
    for (int m = 0; m < 8; ++m) s[8 + m] += c * bf2f((ushort_t)u1[m]);
  }
#pragma unroll
  for (int m = 0; m < 16; ++m) {
    float val = s[m];
#pragma unroll
    for (int off = 32; off > 0; off >>= 1) val += __shfl_down(val, off);
    s[m] = val;
  }
  if (t == 0) {
    float sq = 0.f;
#pragma unroll
    for (int m = 0; m < 16; ++m) {
      s[m] += caps_bias[q * 16 + m];
      sq += s[m] * s[m];
    }
    float coef = (sq / (1.f + sq)) * rsqrtf(sq + 1e-9f);
    float vl2 = 0.f;
#pragma unroll
    for (int m = 0; m < 16; ++m) {
      float vv = coef * s[m];
      v[bq * 16 + m] = vv;
      vl2 += vv * vv;
    }
    if (MODE == 2) out[bq] = sqrtf(vl2 + 1e-9f);
  }
}

// ======== agree: d=u.v, bij update, fused softmax -> c ========
// thread = (b,p); bij [b][p][10]; c [b][q][p].
template <bool FIRST>
__global__ __launch_bounds__(256) void agree_kernel(
    const ushort_t* __restrict__ uh, const float* __restrict__ v,
    float* __restrict__ bij, float* __restrict__ cbuf) {
  int tid = blockIdx.x * 256 + threadIdx.x;
  int b = tid / 1152;
  int p = tid - b * 1152;
  float br[10];
  float* bp = &bij[(size_t)tid * 10];
#pragma unroll
  for (int q = 0; q < 10; ++q) {
    const ushort_t* ub = &uh[(size_t)((b * 10 + q) * 1152 + p) * 16];
    short8 u0 = *(const short8*)ub;
    short8 u1 = *(const short8*)(ub + 8);
    const float4* v4 = reinterpret_cast<const float4*>(&v[(b * 10 + q) * 16]);
    float4 b0 = v4[0], b1 = v4[1], b2 = v4[2], b3 = v4[3];
    float d = bf2f((ushort_t)u0[0]) * b0.x + bf2f((ushort_t)u0[1]) * b0.y
            + bf2f((ushort_t)u0[2]) * b0.z + bf2f((ushort_t)u0[3]) * b0.w
            + bf2f((ushort_t)u0[4]) * b1.x + bf2f((ushort_t)u0[5]) * b1.y
            + bf2f((ushort_t)u0[6]) * b1.z + bf2f((ushort_t)u0[7]) * b1.w
            + bf2f((ushort_t)u1[0]) * b2.x + bf2f((ushort_t)u1[1]) * b2.y
            + bf2f((ushort_t)u1[2]) * b2.z + bf2f((ushort_t)u1[3]) * b2.w
            + bf2f((ushort_t)u1[4]) * b3.x + bf2f((ushort_t)u1[5]) * b3.y
            + bf2f((ushort_t)u1[6]) * b3.z + bf2f((ushort_t)u1[7]) * b3.w;
    br[q] = (FIRST ? 0.f : bp[q]) + d;
  }
  float mx = br[0];
#pragma unroll
  for (int q = 1; q < 10; ++q) mx = fmaxf(mx, br[q]);
  float den = 0.f;
  float ex[10];
#pragma unroll
  for (int q = 0; q < 10; ++q) { ex[q] = __expf(br[q] - mx); den += ex[q]; }
  float inv = 1.f / den;
#pragma unroll
  for (int q = 0; q < 10; ++q) {
    bp[q] = br[q];
    cbuf[(size_t)(b * 10 + q) * 1152 + p] = ex[q] * inv;
  }
}

// ================= fc1: masked_v + fc1 =================
__global__ __launch_bounds__(128) void fc1_kernel(
    const float* __restrict__ v, const float* __restrict__ y,
    const float* __restrict__ fc1_w, const float* __restrict__ fc1_b,
    float* __restrict__ f1g) {
  int b = blockIdx.x, t = threadIdx.x;
  __shared__ float mv[16];
  if (t < 16) {
    const float* vb = &v[b * 160];
    float a = 0.f;
#pragma unroll
    for (int tt = 0; tt < 10; ++tt) a += vb[t * 10 + tt] * y[b * 10 + tt];
    mv[t] = a;
  }
  __syncthreads();
  for (int o = t; o < 512; o += 128) {
    const float4* wr = reinterpret_cast<const float4*>(&fc1_w[o * 16]);
    float4 w0 = wr[0], w1 = wr[1], w2 = wr[2], w3 = wr[3];
    f1g[b * 512 + o] = fc1_b[o]
        + mv[0] * w0.x + mv[1] * w0.y + mv[2] * w0.z + mv[3] * w0.w
        + mv[4] * w1.x + mv[5] * w1.y + mv[6] * w1.z + mv[7] * w1.w
        + mv[8] * w2.x + mv[9] * w2.y + mv[10] * w2.z + mv[11] * w2.w
        + mv[12] * w3.x + mv[13] * w3.y + mv[14] * w3.z + mv[15] * w3.w;
  }
}

// ================= fc2 =================
// grid 512: b = blk>>2, o = (blk&3)*256 + t
__global__ __launch_bounds__(256) void fc2_kernel(
    const float* __restrict__ f1g, const float* __restrict__ fc2_w,
    const float* __restrict__ fc2_b, float* __restrict__ f2g) {
  int b = blockIdx.x >> 2;
  int o = (blockIdx.x & 3) * 256 + threadIdx.x;
  __shared__ float f1[512];
  for (int l = threadIdx.x; l < 512; l += 256) f1[l] = f1g[b * 512 + l];
  __syncthreads();
  const float4* wr = reinterpret_cast<const float4*>(&fc2_w[o * 512]);
  float a = fc2_b[o];
#pragma unroll 4
  for (int k4 = 0; k4 < 128; ++k4) {
    float4 w4 = wr[k4];
    a += f1[4 * k4] * w4.x + f1[4 * k4 + 1] * w4.y + f1[4 * k4 + 2] * w4.z +
         f1[4 * k4 + 3] * w4.w;
  }
  f2g[b * 1024 + o] = a;
}

// ================= fc3 + sigmoid =================
// grid 512: b = blk>>2, o = (blk&3)*196 + t (t<196)
__global__ __launch_bounds__(256) void fc3_kernel(
    const float* __restrict__ f2g, const float* __restrict__ fc3_w,
    const float* __restrict__ fc3_b, float* __restrict__ out) {
  int b = blockIdx.x >> 2;
  int oc = (blockIdx.x & 3) * 196;
  __shared__ float f2[1024];
  for (int l = threadIdx.x; l < 1024; l += 256) f2[l] = f2g[b * 1024 + l];
  __syncthreads();
  if (threadIdx.x >= 196) return;
  int o = oc + threadIdx.x;
  const float4* wr = reinterpret_cast<const float4*>(&fc3_w[o * 1024]);
  float a = fc3_b[o];
#pragma unroll 4
  for (int k4 = 0; k4 < 256; ++k4) {
    float4 w4 = wr[k4];
    a += f2[4 * k4] * w4.x + f2[4 * k4 + 1] * w4.y + f2[4 * k4 + 2] * w4.z +
         f2[4 * k4 + 3] * w4.w;
  }
  out[1280 + b * 784 + o] = 1.f / (1.f + __expf(-a));
}

extern "C" void kernel_launch(void* const* d_in, const int* in_sizes, int n_in,
                              void* d_out, int out_size, void* d_ws, size_t ws_size,
                              hipStream_t stream) {
  const float* x       = (const float*)d_in[0];
  const float* y       = (const float*)d_in[1];
  const float* conv1_w = (const float*)d_in[2];
  const float* conv1_b = (const float*)d_in[3];
  const float* caps1_w = (const float*)d_in[4];
  const float* caps1_b = (const float*)d_in[5];
  const float* W       = (const float*)d_in[6];
  const float* cbias   = (const float*)d_in[7];
  const float* fc1_w   = (const float*)d_in[8];
  const float* fc1_b   = (const float*)d_in[9];
  const float* fc2_w   = (const float*)d_in[10];
  const float* fc2_b   = (const float*)d_in[11];
  const float* fc3_w   = (const float*)d_in[12];
  const float* fc3_b   = (const float*)d_in[13];
  float* out = (float*)d_out;

  char* wsb = (char*)d_ws;
  ushort_t* h1t  = (ushort_t*)(wsb + OFFB_H1T);
  ushort_t* wt   = (ushort_t*)(wsb + OFFB_WT);
  float*    part = (float*)(wsb + OFFB_PART);
  float*    h2   = (float*)(wsb + OFFB_H2);
  ushort_t* uh   = (ushort_t*)(wsb + OFFB_UH);
  float*    bij  = (float*)(wsb + OFFB_BIJ);
  float*    c    = (float*)(wsb + OFFB_C);
  float*    v    = (float*)(wsb + OFFB_V);
  float*    f1   = (float*)(wsb + OFFB_F1);
  float*    f2   = (float*)(wsb + OFFB_F2);

  conv1_kernel<<<2560, 256, 0, stream>>>(x, conv1_w, conv1_b, h1t);
  wreorder_kernel<<<256, 256, 0, stream>>>(caps1_w, wt);
  caps1_gemm<<<1152, 256, 0, stream>>>(h1t, wt, part);
  reduce_kernel<<<4608, 256, 0, stream>>>(part, caps1_b, h2);
  uhat_kernel<<<5760, 256, 0, stream>>>(h2, W, uh);

  sv_kernel<0><<<1280, 64, 0, stream>>>(uh, c, cbias, v, out);
  agree_kernel<true><<<576, 256, 0, stream>>>(uh, v, bij, c);
  sv_kernel<1><<<1280, 64, 0, stream>>>(uh, c, cbias, v, out);
  agree_kernel<false><<<576, 256, 0, stream>>>(uh, v, bij, c);
  sv_kernel<2><<<1280, 64, 0, stream>>>(uh, c, cbias, v, out);

  fc1_kernel<<<128, 128, 0, stream>>>(v, y, fc1_w, fc1_b, f1);
  fc2_kernel<<<512, 256, 0, stream>>>(f1, fc2_w, fc2_b, f2);
  fc3_kernel<<<512, 256, 0, stream>>>(f2, fc3_w, fc3_b, out);
}

// Round 7
// 341.908 us; speedup vs baseline: 8.0078x; 1.2520x over previous
//
#include <hip/hip_runtime.h>
#include <hip/hip_bf16.h>

typedef unsigned short ushort_t;
typedef __attribute__((ext_vector_type(8))) short short8;
typedef __attribute__((ext_vector_type(4))) float f32x4;

// ---------------- problem constants ----------------
// conv1: x[128,1,28,28]*w[256,1,9,9] s1 -> h1t[128,20,20,256] (NHWC bf16)
// caps1: implicit GEMM M=4608(b,pos) N=256(co) K=81*256, split-K x4
//        -> part[4][4608][256] f32 -> reduce -> h2[m=b*36+pos][n=co] f32
// u_hat: materialized bf16 [b][q][p][16]; routing p=1152, q=10; output f32.

// ---------------- ws layout (bytes) ----------------
#define OFFB_H1T  0u           // 26,214,400
#define OFFB_WT   26214400u    // 10,616,832
#define OFFB_PART 36831232u    // 18,874,368
#define OFFB_H2   55705600u    //  4,718,592
#define OFFB_UH   60424192u    // 47,185,920
#define OFFB_BIJ  107610112u   //  5,898,240
#define OFFB_C    113508352u   //  5,898,240
#define OFFB_V    119406592u   //     81,920
#define OFFB_F1   119488512u   //    262,144
#define OFFB_F2   119750656u   //    524,288  -> total 120.3 MB

__device__ __forceinline__ ushort_t f2bf(float f) {
  union { float f; unsigned int u; } c; c.f = f;
  unsigned int r = (c.u + 0x7FFFu + ((c.u >> 16) & 1u)) >> 16;
  return (ushort_t)r;
}
__device__ __forceinline__ float bf2f(ushort_t u) {
  union { unsigned int i; float f; } c; c.i = ((unsigned int)u) << 16;
  return c.f;
}

// ================= conv1 + relu -> NHWC bf16 =================
// grid = b*20+oy (2560), block 256 (t = co).
__global__ __launch_bounds__(256) void conv1_kernel(
    const float* __restrict__ x, const float* __restrict__ w,
    const float* __restrict__ bias, ushort_t* __restrict__ h1t) {
  int blk = blockIdx.x;
  int b = blk / 20, oy = blk % 20;
  int co = threadIdx.x;
  __shared__ float xs[252];
  for (int l = co; l < 252; l += 256)
    xs[l] = x[b * 784 + (oy + l / 28) * 28 + (l % 28)];
  __syncthreads();
  float bs = bias[co];
  float acc[20];
#pragma unroll
  for (int i = 0; i < 20; ++i) acc[i] = bs;
  for (int ky = 0; ky < 9; ++ky) {
    float xr[28];
#pragma unroll
    for (int i = 0; i < 28; ++i) xr[i] = xs[ky * 28 + i];
    float wk[9];
#pragma unroll
    for (int kx = 0; kx < 9; ++kx) wk[kx] = w[co * 81 + ky * 9 + kx];
#pragma unroll
    for (int kx = 0; kx < 9; ++kx)
#pragma unroll
      for (int ox = 0; ox < 20; ++ox) acc[ox] += wk[kx] * xr[ox + kx];
  }
  int xb = (b * 20 + oy) * 20;
#pragma unroll
  for (int ox = 0; ox < 20; ++ox)
    h1t[(xb + ox) * 256 + co] = f2bf(fmaxf(acc[ox], 0.f));
}

// ========== weight reorder via LDS transpose (both sides coalesced) =======
// block = co; wl[ci][82] padded (stride 41 words, gcd(41,32)=1 -> no conflict)
__global__ __launch_bounds__(256) void wreorder_kernel(
    const float* __restrict__ w, ushort_t* __restrict__ wt) {
  int co = blockIdx.x;
  __shared__ ushort_t wl[256 * 82];
  int t = threadIdx.x;
  const float* src = w + (size_t)co * 20736;
  for (int e = t; e < 20736; e += 256) {
    int ci = e / 81, kk = e - ci * 81;
    wl[ci * 82 + kk] = f2bf(src[e]);
  }
  __syncthreads();
  for (int kk = 0; kk < 81; ++kk)
    wt[((size_t)kk * 256 + co) * 256 + t] = wl[t * 82 + kk];
}

// ================= caps1 implicit GEMM, split-K x4 =================
__global__ __launch_bounds__(256) void caps1_gemm(
    const ushort_t* __restrict__ h1t, const ushort_t* __restrict__ wt,
    float* __restrict__ part) {
  int blk = blockIdx.x;
  int chunk = blk / 288;
  int tile = blk - chunk * 288;
  int gm0 = (tile >> 2) * 64;
  int gn0 = (tile & 3) * 64;
  int ks0 = chunk * 81, ks1 = ks0 + 81;
  int t = threadIdx.x;
  int wave = t >> 6, lane = t & 63;
  int wm = (wave >> 1) * 32, wn = (wave & 1) * 32;
  int lr = lane & 15, lg = lane >> 4;

  __shared__ __align__(16) ushort_t As[2][64 * 72];
  __shared__ __align__(16) ushort_t Bs[2][64 * 72];

  int r = t >> 2, seg = t & 3;
  int m = gm0 + r;
  int b = m / 36, pos = m - b * 36;
  int oy = pos / 6, ox = pos - oy * 6;
  const ushort_t* arow = h1t + ((b * 20 + 2 * oy) * 20 + 2 * ox) * 256 + seg * 16;
  const ushort_t* brow = wt + (gn0 + r) * 256 + seg * 16;
  int lds_off = r * 72 + seg * 16;

  f32x4 acc[2][2];
#pragma unroll
  for (int i = 0; i < 2; ++i)
#pragma unroll
    for (int j = 0; j < 2; ++j)
#pragma unroll
      for (int e = 0; e < 4; ++e) acc[i][j][e] = 0.f;

  float4 ra0, ra1, rb0, rb1;
  {
    int kk = ks0 >> 2, ci0 = (ks0 & 3) << 6;
    int ky = kk / 9, kx = kk - ky * 9;
    const ushort_t* ap = arow + (ky * 20 + kx) * 256 + ci0;
    ra0 = *(const float4*)(ap);
    ra1 = *(const float4*)(ap + 8);
    const ushort_t* bp = brow + kk * 65536 + ci0;
    rb0 = *(const float4*)(bp);
    rb1 = *(const float4*)(bp + 8);
  }
  *(float4*)&As[0][lds_off] = ra0;
  *(float4*)&As[0][lds_off + 8] = ra1;
  *(float4*)&Bs[0][lds_off] = rb0;
  *(float4*)&Bs[0][lds_off + 8] = rb1;
  __syncthreads();

  int buf = 0;
  for (int ks = ks0; ks < ks1; ++ks) {
    int nxt = ks + 1;
    if (nxt < ks1) {
      int kk = nxt >> 2, ci0 = (nxt & 3) << 6;
      int ky = kk / 9, kx = kk - ky * 9;
      const ushort_t* ap = arow + (ky * 20 + kx) * 256 + ci0;
      ra0 = *(const float4*)(ap);
      ra1 = *(const float4*)(ap + 8);
      const ushort_t* bp = brow + kk * 65536 + ci0;
      rb0 = *(const float4*)(bp);
      rb1 = *(const float4*)(bp + 8);
    }
    short8 af[2][2], bfr[2][2];
#pragma unroll
    for (int kh = 0; kh < 2; ++kh) {
#pragma unroll
      for (int mf = 0; mf < 2; ++mf)
        af[mf][kh] = *(const short8*)&As[buf][(wm + mf * 16 + lr) * 72 + kh * 32 + lg * 8];
#pragma unroll
      for (int nf = 0; nf < 2; ++nf)
        bfr[nf][kh] = *(const short8*)&Bs[buf][(wn + nf * 16 + lr) * 72 + kh * 32 + lg * 8];
    }
#pragma unroll
    for (int kh = 0; kh < 2; ++kh)
#pragma unroll
      for (int mf = 0; mf < 2; ++mf)
#pragma unroll
        for (int nf = 0; nf < 2; ++nf)
          acc[mf][nf] = __builtin_amdgcn_mfma_f32_16x16x32_bf16(
              af[mf][kh], bfr[nf][kh], acc[mf][nf], 0, 0, 0);
    __syncthreads();
    if (nxt < ks1) {
      int nb = buf ^ 1;
      *(float4*)&As[nb][lds_off] = ra0;
      *(float4*)&As[nb][lds_off + 8] = ra1;
      *(float4*)&Bs[nb][lds_off] = rb0;
      *(float4*)&Bs[nb][lds_off + 8] = rb1;
      __syncthreads();
    }
    buf ^= 1;
  }

#pragma unroll
  for (int mf = 0; mf < 2; ++mf)
#pragma unroll
    for (int nf = 0; nf < 2; ++nf) {
      int nn = gn0 + wn + nf * 16 + lr;
#pragma unroll
      for (int reg = 0; reg < 4; ++reg) {
        int mm = gm0 + wm + mf * 16 + lg * 4 + reg;
        part[((size_t)chunk * 4608 + mm) * 256 + nn] = acc[mf][nf][reg];
      }
    }
}

// ========= reduce: h2[m][n] = relu(sum_c part[c][m][n] + bias[n]) =========
__global__ __launch_bounds__(256) void reduce_kernel(
    const float* __restrict__ part, const float* __restrict__ bias,
    float* __restrict__ h2) {
  int m = blockIdx.x;
  int n = threadIdx.x;
  size_t o = (size_t)m * 256 + n;
  float s = part[o] + part[o + 4608 * 256] + part[o + 2 * 4608 * 256] +
            part[o + 3 * 4608 * 256];
  h2[o] = fmaxf(s + bias[n], 0.f);
}

// ================= u_hat materialize v2 (W-local, LDS-staged) ============
// grid = ((q*72 + pc)*2 + bh), 1440 blocks, 256 threads.
// Each block: q fixed, p in [p0,p0+16), b in [b0,b0+64).
// W staged once grid-wide (each row read by exactly one block).
__global__ __launch_bounds__(256) void uhat_kernel(
    const float* __restrict__ h2, const float* __restrict__ W,
    ushort_t* __restrict__ uh) {
  int blk = blockIdx.x;
  int bh = blk & 1;
  int qpc = blk >> 1;
  int q = qpc / 72;
  int pc = qpc - q * 72;
  int p0 = pc * 16;
  int b0 = bh * 64;
  __shared__ float Wl[16][132];     // pad 128->132: 2-way max (free)
  __shared__ float xl[64][16][9];   // pad 8->9: exactly 2-way (free)
  int t = threadIdx.x;
  // stage W: 16 rows x 128 f32, fully coalesced float4
#pragma unroll
  for (int it = 0; it < 2; ++it) {
    int idx = t * 2 + it;          // 0..511
    int row = idx >> 5;            // 0..15
    int c4 = idx & 31;             // 0..31
    float4 vv = *(reinterpret_cast<const float4*>(
        &W[(size_t)((p0 + row) * 10 + q) * 128]) + c4);
    Wl[row][c4 * 4 + 0] = vv.x;
    Wl[row][c4 * 4 + 1] = vv.y;
    Wl[row][c4 * 4 + 2] = vv.z;
    Wl[row][c4 * 4 + 3] = vv.w;
  }
  // stage x_view slice: xv = h2[(b*36 + f%36)*256 + f/360], f=(p0+i)*80+q*8+n
  for (int j = 0; j < 32; ++j) {
    int e = t + 256 * j;           // 0..8191
    int b_l = e >> 7;
    int rem = e & 127;
    int i = rem >> 3, n = rem & 7;
    int f = (p0 + i) * 80 + q * 8 + n;
    xl[b_l][i][n] = h2[((size_t)(b0 + b_l) * 36 + (f % 36)) * 256 + (f / 360)];
  }
  __syncthreads();
  int p_l = t & 15;
  int b_ll = t >> 4;
  const float* wr = &Wl[p_l][0];
#pragma unroll
  for (int k = 0; k < 4; ++k) {
    int b_l = b_ll + 16 * k;
    float xv[8];
#pragma unroll
    for (int n = 0; n < 8; ++n) xv[n] = xl[b_l][p_l][n];
    short8 o0, o1;
#pragma unroll
    for (int a = 0; a < 8; ++a) {
      float ue = 0.f, uo = 0.f;
#pragma unroll
      for (int n = 0; n < 8; ++n) {
        ue += wr[a * 16 + n] * xv[n];
        uo += wr[a * 16 + 8 + n] * xv[n];
      }
      if (a < 4) { o0[2 * a] = (short)f2bf(ue); o0[2 * a + 1] = (short)f2bf(uo); }
      else { o1[2 * (a - 4)] = (short)f2bf(ue); o1[2 * (a - 4) + 1] = (short)f2bf(uo); }
    }
    size_t dst = ((size_t)((b0 + b_l) * 10 + q) * 1152 + p0 + p_l) * 16;
    *(short8*)&uh[dst] = o0;
    *(short8*)&uh[dst + 8] = o1;
  }
}

// ================= sv: weighted sum + squash =================
// MODE 0: c = 0.1 exactly (softmax of zeros); 1: read c; 2: read c + out.
template <int MODE>
__global__ __launch_bounds__(64) void sv_kernel(
    const ushort_t* __restrict__ uh, const float* __restrict__ cbuf,
    const float* __restrict__ caps_bias, float* __restrict__ v,
    float* __restrict__ out) {
  int bq = blockIdx.x;
  int q = bq % 10;
  int t = threadIdx.x;
  const ushort_t* ub = &uh[(size_t)bq * 1152 * 16];
  const float* cb = &cbuf[(size_t)bq * 1152];
  float s[16];
#pragma unroll
  for (int m = 0; m < 16; ++m) s[m] = 0.f;
  for (int p = t; p < 1152; p += 64) {
    short8 u0 = *(const short8*)&ub[p * 16];
    short8 u1 = *(const short8*)&ub[p * 16 + 8];
    float c = (MODE == 0) ? 0.1f : cb[p];
#pragma unroll
    for (int m = 0; m < 8; ++m) s[m] += c * bf2f((ushort_t)u0[m]);
#pragma unroll
    for (int m = 0; m < 8; ++m) s[8 + m] += c * bf2f((ushort_t)u1[m]);
  }
#pragma unroll
  for (int m = 0; m < 16; ++m) {
    float val = s[m];
#pragma unroll
    for (int off = 32; off > 0; off >>= 1) val += __shfl_down(val, off);
    s[m] = val;
  }
  if (t == 0) {
    float sq = 0.f;
#pragma unroll
    for (int m = 0; m < 16; ++m) {
      s[m] += caps_bias[q * 16 + m];
      sq += s[m] * s[m];
    }
    float coef = (sq / (1.f + sq)) * rsqrtf(sq + 1e-9f);
    float vl2 = 0.f;
#pragma unroll
    for (int m = 0; m < 16; ++m) {
      float vv = coef * s[m];
      v[bq * 16 + m] = vv;
      vl2 += vv * vv;
    }
    if (MODE == 2) out[bq] = sqrtf(vl2 + 1e-9f);
  }
}

// ======== agree: d=u.v, bij update, fused softmax -> c ========
template <bool FIRST>
__global__ __launch_bounds__(256) void agree_kernel(
    const ushort_t* __restrict__ uh, const float* __restrict__ v,
    float* __restrict__ bij, float* __restrict__ cbuf) {
  int tid = blockIdx.x * 256 + threadIdx.x;
  int b = tid / 1152;
  int p = tid - b * 1152;
  float br[10];
  float* bp = &bij[(size_t)tid * 10];
#pragma unroll
  for (int q = 0; q < 10; ++q) {
    const ushort_t* ub = &uh[(size_t)((b * 10 + q) * 1152 + p) * 16];
    short8 u0 = *(const short8*)ub;
    short8 u1 = *(const short8*)(ub + 8);
    const float4* v4 = reinterpret_cast<const float4*>(&v[(b * 10 + q) * 16]);
    float4 b0 = v4[0], b1 = v4[1], b2 = v4[2], b3 = v4[3];
    float d = bf2f((ushort_t)u0[0]) * b0.x + bf2f((ushort_t)u0[1]) * b0.y
            + bf2f((ushort_t)u0[2]) * b0.z + bf2f((ushort_t)u0[3]) * b0.w
            + bf2f((ushort_t)u0[4]) * b1.x + bf2f((ushort_t)u0[5]) * b1.y
            + bf2f((ushort_t)u0[6]) * b1.z + bf2f((ushort_t)u0[7]) * b1.w
            + bf2f((ushort_t)u1[0]) * b2.x + bf2f((ushort_t)u1[1]) * b2.y
            + bf2f((ushort_t)u1[2]) * b2.z + bf2f((ushort_t)u1[3]) * b2.w
            + bf2f((ushort_t)u1[4]) * b3.x + bf2f((ushort_t)u1[5]) * b3.y
            + bf2f((ushort_t)u1[6]) * b3.z + bf2f((ushort_t)u1[7]) * b3.w;
    br[q] = (FIRST ? 0.f : bp[q]) + d;
  }
  float mx = br[0];
#pragma unroll
  for (int q = 1; q < 10; ++q) mx = fmaxf(mx, br[q]);
  float den = 0.f;
  float ex[10];
#pragma unroll
  for (int q = 0; q < 10; ++q) { ex[q] = __expf(br[q] - mx); den += ex[q]; }
  float inv = 1.f / den;
#pragma unroll
  for (int q = 0; q < 10; ++q) {
    bp[q] = br[q];
    cbuf[(size_t)(b * 10 + q) * 1152 + p] = ex[q] * inv;
  }
}

// ================= fc1: masked_v + fc1 =================
__global__ __launch_bounds__(128) void fc1_kernel(
    const float* __restrict__ v, const float* __restrict__ y,
    const float* __restrict__ fc1_w, const float* __restrict__ fc1_b,
    float* __restrict__ f1g) {
  int b = blockIdx.x, t = threadIdx.x;
  __shared__ float mv[16];
  if (t < 16) {
    const float* vb = &v[b * 160];
    float a = 0.f;
#pragma unroll
    for (int tt = 0; tt < 10; ++tt) a += vb[t * 10 + tt] * y[b * 10 + tt];
    mv[t] = a;
  }
  __syncthreads();
  for (int o = t; o < 512; o += 128) {
    const float4* wr = reinterpret_cast<const float4*>(&fc1_w[o * 16]);
    float4 w0 = wr[0], w1 = wr[1], w2 = wr[2], w3 = wr[3];
    f1g[b * 512 + o] = fc1_b[o]
        + mv[0] * w0.x + mv[1] * w0.y + mv[2] * w0.z + mv[3] * w0.w
        + mv[4] * w1.x + mv[5] * w1.y + mv[6] * w1.z + mv[7] * w1.w
        + mv[8] * w2.x + mv[9] * w2.y + mv[10] * w2.z + mv[11] * w2.w
        + mv[12] * w3.x + mv[13] * w3.y + mv[14] * w3.z + mv[15] * w3.w;
  }
}

// ================= fc2 =================
__global__ __launch_bounds__(256) void fc2_kernel(
    const float* __restrict__ f1g, const float* __restrict__ fc2_w,
    const float* __restrict__ fc2_b, float* __restrict__ f2g) {
  int b = blockIdx.x >> 2;
  int o = (blockIdx.x & 3) * 256 + threadIdx.x;
  __shared__ float f1[512];
  for (int l = threadIdx.x; l < 512; l += 256) f1[l] = f1g[b * 512 + l];
  __syncthreads();
  const float4* wr = reinterpret_cast<const float4*>(&fc2_w[o * 512]);
  float a = fc2_b[o];
#pragma unroll 4
  for (int k4 = 0; k4 < 128; ++k4) {
    float4 w4 = wr[k4];
    a += f1[4 * k4] * w4.x + f1[4 * k4 + 1] * w4.y + f1[4 * k4 + 2] * w4.z +
         f1[4 * k4 + 3] * w4.w;
  }
  f2g[b * 1024 + o] = a;
}

// ================= fc3 + sigmoid =================
__global__ __launch_bounds__(256) void fc3_kernel(
    const float* __restrict__ f2g, const float* __restrict__ fc3_w,
    const float* __restrict__ fc3_b, float* __restrict__ out) {
  int b = blockIdx.x >> 2;
  int oc = (blockIdx.x & 3) * 196;
  __shared__ float f2[1024];
  for (int l = threadIdx.x; l < 1024; l += 256) f2[l] = f2g[b * 1024 + l];
  __syncthreads();
  if (threadIdx.x >= 196) return;
  int o = oc + threadIdx.x;
  const float4* wr = reinterpret_cast<const float4*>(&fc3_w[o * 1024]);
  float a = fc3_b[o];
#pragma unroll 4
  for (int k4 = 0; k4 < 256; ++k4) {
    float4 w4 = wr[k4];
    a += f2[4 * k4] * w4.x + f2[4 * k4 + 1] * w4.y + f2[4 * k4 + 2] * w4.z +
         f2[4 * k4 + 3] * w4.w;
  }
  out[1280 + b * 784 + o] = 1.f / (1.f + __expf(-a));
}

extern "C" void kernel_launch(void* const* d_in, const int* in_sizes, int n_in,
                              void* d_out, int out_size, void* d_ws, size_t ws_size,
                              hipStream_t stream) {
  const float* x       = (const float*)d_in[0];
  const float* y       = (const float*)d_in[1];
  const float* conv1_w = (const float*)d_in[2];
  const float* conv1_b = (const float*)d_in[3];
  const float* caps1_w = (const float*)d_in[4];
  const float* caps1_b = (const float*)d_in[5];
  const float* W       = (const float*)d_in[6];
  const float* cbias   = (const float*)d_in[7];
  const float* fc1_w   = (const float*)d_in[8];
  const float* fc1_b   = (const float*)d_in[9];
  const float* fc2_w   = (const float*)d_in[10];
  const float* fc2_b   = (const float*)d_in[11];
  const float* fc3_w   = (const float*)d_in[12];
  const float* fc3_b   = (const float*)d_in[13];
  float* out = (float*)d_out;

  char* wsb = (char*)d_ws;
  ushort_t* h1t  = (ushort_t*)(wsb + OFFB_H1T);
  ushort_t* wt   = (ushort_t*)(wsb + OFFB_WT);
  float*    part = (float*)(wsb + OFFB_PART);
  float*    h2   = (float*)(wsb + OFFB_H2);
  ushort_t* uh   = (ushort_t*)(wsb + OFFB_UH);
  float*    bij  = (float*)(wsb + OFFB_BIJ);
  float*    c    = (float*)(wsb + OFFB_C);
  float*    v    = (float*)(wsb + OFFB_V);
  float*    f1   = (float*)(wsb + OFFB_F1);
  float*    f2   = (float*)(wsb + OFFB_F2);

  conv1_kernel<<<2560, 256, 0, stream>>>(x, conv1_w, conv1_b, h1t);
  wreorder_kernel<<<256, 256, 0, stream>>>(caps1_w, wt);
  caps1_gemm<<<1152, 256, 0, stream>>>(h1t, wt, part);
  reduce_kernel<<<4608, 256, 0, stream>>>(part, caps1_b, h2);
  uhat_kernel<<<1440, 256, 0, stream>>>(h2, W, uh);

  sv_kernel<0><<<1280, 64, 0, stream>>>(uh, c, cbias, v, out);
  agree_kernel<true><<<576, 256, 0, stream>>>(uh, v, bij, c);
  sv_kernel<1><<<1280, 64, 0, stream>>>(uh, c, cbias, v, out);
  agree_kernel<false><<<576, 256, 0, stream>>>(uh, v, bij, c);
  sv_kernel<2><<<1280, 64, 0, stream>>>(uh, c, cbias, v, out);

  fc1_kernel<<<128, 128, 0, stream>>>(v, y, fc1_w, fc1_b, f1);
  fc2_kernel<<<512, 256, 0, stream>>>(f1, fc2_w, fc2_b, f2);
  fc3_kernel<<<512, 256, 0, stream>>>(f2, fc3_w, fc3_b, out);
}

// Round 8
// 327.286 us; speedup vs baseline: 8.3656x; 1.0447x over previous
//
#include <hip/hip_runtime.h>
#include <hip/hip_bf16.h>

typedef unsigned short ushort_t;
typedef __attribute__((ext_vector_type(8))) short short8;
typedef __attribute__((ext_vector_type(4))) float f32x4;

// ---------------- problem constants ----------------
// conv1: x[128,1,28,28]*w[256,1,9,9] s1 -> h1t[128,20,20,256] (NHWC bf16)
// caps1: implicit GEMM M=4608(b,pos) N=256(co) K=81*256, split-K by ci-quarter
//        -> part[4][4608][256] f32 -> reduce -> h2[m=b*36+pos][n=co] f32
// u_hat: materialized bf16 [b][q][p][16]; routing p=1152, q=10; output f32.

// ---------------- ws layout (bytes) ----------------
#define OFFB_H1T  0u           // 26,214,400
#define OFFB_WT   26214400u    // 10,616,832
#define OFFB_PART 36831232u    // 18,874,368
#define OFFB_H2   55705600u    //  4,718,592
#define OFFB_UH   60424192u    // 47,185,920
#define OFFB_BIJ  107610112u   //  5,898,240
#define OFFB_C    113508352u   //  5,898,240
#define OFFB_V    119406592u   //     81,920
#define OFFB_F1   119488512u   //    262,144
#define OFFB_F2   119750656u   //    524,288  -> total 120.3 MB

__device__ __forceinline__ ushort_t f2bf(float f) {
  union { float f; unsigned int u; } c; c.f = f;
  unsigned int r = (c.u + 0x7FFFu + ((c.u >> 16) & 1u)) >> 16;
  return (ushort_t)r;
}
__device__ __forceinline__ float bf2f(ushort_t u) {
  union { unsigned int i; float f; } c; c.i = ((unsigned int)u) << 16;
  return c.f;
}

// ================= conv1 + relu -> NHWC bf16 =================
__global__ __launch_bounds__(256) void conv1_kernel(
    const float* __restrict__ x, const float* __restrict__ w,
    const float* __restrict__ bias, ushort_t* __restrict__ h1t) {
  int blk = blockIdx.x;
  int b = blk / 20, oy = blk % 20;
  int co = threadIdx.x;
  __shared__ float xs[252];
  for (int l = co; l < 252; l += 256)
    xs[l] = x[b * 784 + (oy + l / 28) * 28 + (l % 28)];
  __syncthreads();
  float bs = bias[co];
  float acc[20];
#pragma unroll
  for (int i = 0; i < 20; ++i) acc[i] = bs;
  for (int ky = 0; ky < 9; ++ky) {
    float xr[28];
#pragma unroll
    for (int i = 0; i < 28; ++i) xr[i] = xs[ky * 28 + i];
    float wk[9];
#pragma unroll
    for (int kx = 0; kx < 9; ++kx) wk[kx] = w[co * 81 + ky * 9 + kx];
#pragma unroll
    for (int kx = 0; kx < 9; ++kx)
#pragma unroll
      for (int ox = 0; ox < 20; ++ox) acc[ox] += wk[kx] * xr[ox + kx];
  }
  int xb = (b * 20 + oy) * 20;
#pragma unroll
  for (int ox = 0; ox < 20; ++ox)
    h1t[(xb + ox) * 256 + co] = f2bf(fmaxf(acc[ox], 0.f));
}

// ========== weight reorder via LDS transpose (both sides coalesced) =======
__global__ __launch_bounds__(256) void wreorder_kernel(
    const float* __restrict__ w, ushort_t* __restrict__ wt) {
  int co = blockIdx.x;
  __shared__ ushort_t wl[256 * 82];
  int t = threadIdx.x;
  const float* src = w + (size_t)co * 20736;
  for (int e = t; e < 20736; e += 256) {
    int ci = e / 81, kk = e - ci * 81;
    wl[ci * 82 + kk] = f2bf(src[e]);
  }
  __syncthreads();
  for (int kk = 0; kk < 81; ++kk)
    wt[((size_t)kk * 256 + co) * 256 + t] = wl[t * 82 + kk];
}

// ================= caps1 implicit GEMM, split-K by ci-quarter ==============
// 1152 blocks; XCD-bijective swizzle -> each XCD: 36 m-tiles x 4 n-tiles of
// one ci-chunk (B slice 2.65MB + A slice 3.3MB ~ L2-resident per XCD).
// LDS: linear 64x64 tiles with 16B-granule XOR swizzle (g ^= row&7) on both
// the reg-staged write and the fragment read -> 2-way max (free).
__global__ __launch_bounds__(256) void caps1_gemm(
    const ushort_t* __restrict__ h1t, const ushort_t* __restrict__ wt,
    float* __restrict__ part) {
  int lb = (blockIdx.x & 7) * 144 + (blockIdx.x >> 3);  // bijective, 1152%8==0
  int chunk = lb / 288;            // ci quarter
  int tile = lb - chunk * 288;
  int gm0 = (tile >> 2) * 64;
  int gn0 = (tile & 3) * 64;
  int ci0 = chunk << 6;
  int t = threadIdx.x;
  int wave = t >> 6, lane = t & 63;
  int wm = (wave >> 1) * 32, wn = (wave & 1) * 32;
  int lr = lane & 15, lg = lane >> 4;

  __shared__ __align__(16) ushort_t As[2][64 * 64];
  __shared__ __align__(16) ushort_t Bs[2][64 * 64];

  int r = t >> 2, seg = t & 3;
  int m = gm0 + r;
  int b = m / 36, pos = m - b * 36;
  int oy = pos / 6, ox = pos - oy * 6;
  const ushort_t* arow = h1t + ((b * 20 + 2 * oy) * 20 + 2 * ox) * 256 + ci0 + seg * 16;
  const ushort_t* brow = wt + (gn0 + r) * 256 + ci0 + seg * 16;
  // swizzled LDS store offsets (granules 2seg, 2seg+1 of row r)
  int rx = r & 7;
  int st0 = r * 64 + (((seg << 1) | 0) ^ rx) * 8;
  int st1 = r * 64 + (((seg << 1) | 1) ^ rx) * 8;
  // swizzled fragment-read offsets: slot(kh) = ((kh*4+lg) ^ (lr&7)) * 8
  int lx = lr & 7;
  int sl0 = ((0 * 4 + lg) ^ lx) * 8;
  int sl1 = ((1 * 4 + lg) ^ lx) * 8;

  f32x4 acc[2][2];
#pragma unroll
  for (int i = 0; i < 2; ++i)
#pragma unroll
    for (int j = 0; j < 2; ++j)
#pragma unroll
      for (int e = 0; e < 4; ++e) acc[i][j][e] = 0.f;

  float4 ra0, ra1, rb0, rb1;
  // prologue: stage kk=0
  ra0 = *(const float4*)(arow);
  ra1 = *(const float4*)(arow + 8);
  rb0 = *(const float4*)(brow);
  rb1 = *(const float4*)(brow + 8);
  *(float4*)&As[0][st0] = ra0;
  *(float4*)&As[0][st1] = ra1;
  *(float4*)&Bs[0][st0] = rb0;
  *(float4*)&Bs[0][st1] = rb1;
  __syncthreads();

  int buf = 0;
  for (int kk = 0; kk < 81; ++kk) {
    int nxt = kk + 1;
    if (nxt < 81) {
      int ky = nxt / 9, kx = nxt - ky * 9;
      const ushort_t* ap = arow + (ky * 20 + kx) * 256;
      ra0 = *(const float4*)(ap);
      ra1 = *(const float4*)(ap + 8);
      const ushort_t* bp = brow + nxt * 65536;
      rb0 = *(const float4*)(bp);
      rb1 = *(const float4*)(bp + 8);
    }
    short8 af[2][2], bfr[2][2];
#pragma unroll
    for (int mf = 0; mf < 2; ++mf) {
      int ra = (wm + mf * 16 + lr) * 64;
      af[mf][0] = *(const short8*)&As[buf][ra + sl0];
      af[mf][1] = *(const short8*)&As[buf][ra + sl1];
    }
#pragma unroll
    for (int nf = 0; nf < 2; ++nf) {
      int rb = (wn + nf * 16 + lr) * 64;
      bfr[nf][0] = *(const short8*)&Bs[buf][rb + sl0];
      bfr[nf][1] = *(const short8*)&Bs[buf][rb + sl1];
    }
#pragma unroll
    for (int kh = 0; kh < 2; ++kh)
#pragma unroll
      for (int mf = 0; mf < 2; ++mf)
#pragma unroll
        for (int nf = 0; nf < 2; ++nf)
          acc[mf][nf] = __builtin_amdgcn_mfma_f32_16x16x32_bf16(
              af[mf][kh], bfr[nf][kh], acc[mf][nf], 0, 0, 0);
    __syncthreads();
    if (nxt < 81) {
      int nb = buf ^ 1;
      *(float4*)&As[nb][st0] = ra0;
      *(float4*)&As[nb][st1] = ra1;
      *(float4*)&Bs[nb][st0] = rb0;
      *(float4*)&Bs[nb][st1] = rb1;
      __syncthreads();
    }
    buf ^= 1;
  }

#pragma unroll
  for (int mf = 0; mf < 2; ++mf)
#pragma unroll
    for (int nf = 0; nf < 2; ++nf) {
      int nn = gn0 + wn + nf * 16 + lr;
#pragma unroll
      for (int reg = 0; reg < 4; ++reg) {
        int mm = gm0 + wm + mf * 16 + lg * 4 + reg;
        part[((size_t)chunk * 4608 + mm) * 256 + nn] = acc[mf][nf][reg];
      }
    }
}

// ========= reduce: h2[m][n] = relu(sum_c part[c][m][n] + bias[n]) =========
__global__ __launch_bounds__(256) void reduce_kernel(
    const float* __restrict__ part, const float* __restrict__ bias,
    float* __restrict__ h2) {
  int m = blockIdx.x;
  int n = threadIdx.x;
  size_t o = (size_t)m * 256 + n;
  float s = part[o] + part[o + 4608 * 256] + part[o + 2 * 4608 * 256] +
            part[o + 3 * 4608 * 256];
  h2[o] = fmaxf(s + bias[n], 0.f);
}

// ================= u_hat materialize v2 (W-local, LDS-staged) ============
__global__ __launch_bounds__(256) void uhat_kernel(
    const float* __restrict__ h2, const float* __restrict__ W,
    ushort_t* __restrict__ uh) {
  int blk = blockIdx.x;
  int bh = blk & 1;
  int qpc = blk >> 1;
  int q = qpc / 72;
  int pc = qpc - q * 72;
  int p0 = pc * 16;
  int b0 = bh * 64;
  __shared__ float Wl[16][132];
  __shared__ float xl[64][16][9];
  int t = threadIdx.x;
#pragma unroll
  for (int it = 0; it < 2; ++it) {
    int idx = t * 2 + it;
    int row = idx >> 5;
    int c4 = idx & 31;
    float4 vv = *(reinterpret_cast<const float4*>(
        &W[(size_t)((p0 + row) * 10 + q) * 128]) + c4);
    Wl[row][c4 * 4 + 0] = vv.x;
    Wl[row][c4 * 4 + 1] = vv.y;
    Wl[row][c4 * 4 + 2] = vv.z;
    Wl[row][c4 * 4 + 3] = vv.w;
  }
  for (int j = 0; j < 32; ++j) {
    int e = t + 256 * j;
    int b_l = e >> 7;
    int rem = e & 127;
    int i = rem >> 3, n = rem & 7;
    int f = (p0 + i) * 80 + q * 8 + n;
    xl[b_l][i][n] = h2[((size_t)(b0 + b_l) * 36 + (f % 36)) * 256 + (f / 360)];
  }
  __syncthreads();
  int p_l = t & 15;
  int b_ll = t >> 4;
  const float* wr = &Wl[p_l][0];
#pragma unroll
  for (int k = 0; k < 4; ++k) {
    int b_l = b_ll + 16 * k;
    float xv[8];
#pragma unroll
    for (int n = 0; n < 8; ++n) xv[n] = xl[b_l][p_l][n];
    short8 o0, o1;
#pragma unroll
    for (int a = 0; a < 8; ++a) {
      float ue = 0.f, uo = 0.f;
#pragma unroll
      for (int n = 0; n < 8; ++n) {
        ue += wr[a * 16 + n] * xv[n];
        uo += wr[a * 16 + 8 + n] * xv[n];
      }
      if (a < 4) { o0[2 * a] = (short)f2bf(ue); o0[2 * a + 1] = (short)f2bf(uo); }
      else { o1[2 * (a - 4)] = (short)f2bf(ue); o1[2 * (a - 4) + 1] = (short)f2bf(uo); }
    }
    size_t dst = ((size_t)((b0 + b_l) * 10 + q) * 1152 + p0 + p_l) * 16;
    *(short8*)&uh[dst] = o0;
    *(short8*)&uh[dst + 8] = o1;
  }
}

// ================= sv: weighted sum + squash =================
template <int MODE>
__global__ __launch_bounds__(64) void sv_kernel(
    const ushort_t* __restrict__ uh, const float* __restrict__ cbuf,
    const float* __restrict__ caps_bias, float* __restrict__ v,
    float* __restrict__ out) {
  int bq = blockIdx.x;
  int q = bq % 10;
  int t = threadIdx.x;
  const ushort_t* ub = &uh[(size_t)bq * 1152 * 16];
  const float* cb = &cbuf[(size_t)bq * 1152];
  float s[16];
#pragma unroll
  for (int m = 0; m < 16; ++m) s[m] = 0.f;
  for (int p = t; p < 1152; p += 64) {
    short8 u0 = *(const short8*)&ub[p * 16];
    short8 u1 = *(const short8*)&ub[p * 16 + 8];
    float c = (MODE == 0) ? 0.1f : cb[p];
#pragma unroll
    for (int m = 0; m < 8; ++m) s[m] += c * bf2f((ushort_t)u0[m]);
#pragma unroll
    for (int m = 0; m < 8; ++m) s[8 + m] += c * bf2f((ushort_t)u1[m]);
  }
#pragma unroll
  for (int m = 0; m < 16; ++m) {
    float val = s[m];
#pragma unroll
    for (int off = 32; off > 0; off >>= 1) val += __shfl_down(val, off);
    s[m] = val;
  }
  if (t == 0) {
    float sq = 0.f;
#pragma unroll
    for (int m = 0; m < 16; ++m) {
      s[m] += caps_bias[q * 16 + m];
      sq += s[m] * s[m];
    }
    float coef = (sq / (1.f + sq)) * rsqrtf(sq + 1e-9f);
    float vl2 = 0.f;
#pragma unroll
    for (int m = 0; m < 16; ++m) {
      float vv = coef * s[m];
      v[bq * 16 + m] = vv;
      vl2 += vv * vv;
    }
    if (MODE == 2) out[bq] = sqrtf(vl2 + 1e-9f);
  }
}

// ======== agree: d=u.v, bij update, fused softmax -> c ========
template <bool FIRST>
__global__ __launch_bounds__(256) void agree_kernel(
    const ushort_t* __restrict__ uh, const float* __restrict__ v,
    float* __restrict__ bij, float* __restrict__ cbuf) {
  int tid = blockIdx.x * 256 + threadIdx.x;
  int b = tid / 1152;
  int p = tid - b * 1152;
  float br[10];
  float* bp = &bij[(size_t)tid * 10];
#pragma unroll
  for (int q = 0; q < 10; ++q) {
    const ushort_t* ub = &uh[(size_t)((b * 10 + q) * 1152 + p) * 16];
    short8 u0 = *(const short8*)ub;
    short8 u1 = *(const short8*)(ub + 8);
    const float4* v4 = reinterpret_cast<const float4*>(&v[(b * 10 + q) * 16]);
    float4 b0 = v4[0], b1 = v4[1], b2 = v4[2], b3 = v4[3];
    float d = bf2f((ushort_t)u0[0]) * b0.x + bf2f((ushort_t)u0[1]) * b0.y
            + bf2f((ushort_t)u0[2]) * b0.z + bf2f((ushort_t)u0[3]) * b0.w
            + bf2f((ushort_t)u0[4]) * b1.x + bf2f((ushort_t)u0[5]) * b1.y
            + bf2f((ushort_t)u0[6]) * b1.z + bf2f((ushort_t)u0[7]) * b1.w
            + bf2f((ushort_t)u1[0]) * b2.x + bf2f((ushort_t)u1[1]) * b2.y
            + bf2f((ushort_t)u1[2]) * b2.z + bf2f((ushort_t)u1[3]) * b2.w
            + bf2f((ushort_t)u1[4]) * b3.x + bf2f((ushort_t)u1[5]) * b3.y
            + bf2f((ushort_t)u1[6]) * b3.z + bf2f((ushort_t)u1[7]) * b3.w;
    br[q] = (FIRST ? 0.f : bp[q]) + d;
  }
  float mx = br[0];
#pragma unroll
  for (int q = 1; q < 10; ++q) mx = fmaxf(mx, br[q]);
  float den = 0.f;
  float ex[10];
#pragma unroll
  for (int q = 0; q < 10; ++q) { ex[q] = __expf(br[q] - mx); den += ex[q]; }
  float inv = 1.f / den;
#pragma unroll
  for (int q = 0; q < 10; ++q) {
    bp[q] = br[q];
    cbuf[(size_t)(b * 10 + q) * 1152 + p] = ex[q] * inv;
  }
}

// ================= fc1: masked_v + fc1 =================
__global__ __launch_bounds__(128) void fc1_kernel(
    const float* __restrict__ v, const float* __restrict__ y,
    const float* __restrict__ fc1_w, const float* __restrict__ fc1_b,
    float* __restrict__ f1g) {
  int b = blockIdx.x, t = threadIdx.x;
  __shared__ float mv[16];
  if (t < 16) {
    const float* vb = &v[b * 160];
    float a = 0.f;
#pragma unroll
    for (int tt = 0; tt < 10; ++tt) a += vb[t * 10 + tt] * y[b * 10 + tt];
    mv[t] = a;
  }
  __syncthreads();
  for (int o = t; o < 512; o += 128) {
    const float4* wr = reinterpret_cast<const float4*>(&fc1_w[o * 16]);
    float4 w0 = wr[0], w1 = wr[1], w2 = wr[2], w3 = wr[3];
    f1g[b * 512 + o] = fc1_b[o]
        + mv[0] * w0.x + mv[1] * w0.y + mv[2] * w0.z + mv[3] * w0.w
        + mv[4] * w1.x + mv[5] * w1.y + mv[6] * w1.z + mv[7] * w1.w
        + mv[8] * w2.x + mv[9] * w2.y + mv[10] * w2.z + mv[11] * w2.w
        + mv[12] * w3.x + mv[13] * w3.y + mv[14] * w3.z + mv[15] * w3.w;
  }
}

// ================= fc2 =================
__global__ __launch_bounds__(256) void fc2_kernel(
    const float* __restrict__ f1g, const float* __restrict__ fc2_w,
    const float* __restrict__ fc2_b, float* __restrict__ f2g) {
  int b = blockIdx.x >> 2;
  int o = (blockIdx.x & 3) * 256 + threadIdx.x;
  __shared__ float f1[512];
  for (int l = threadIdx.x; l < 512; l += 256) f1[l] = f1g[b * 512 + l];
  __syncthreads();
  const float4* wr = reinterpret_cast<const float4*>(&fc2_w[o * 512]);
  float a = fc2_b[o];
#pragma unroll 4
  for (int k4 = 0; k4 < 128; ++k4) {
    float4 w4 = wr[k4];
    a += f1[4 * k4] * w4.x + f1[4 * k4 + 1] * w4.y + f1[4 * k4 + 2] * w4.z +
         f1[4 * k4 + 3] * w4.w;
  }
  f2g[b * 1024 + o] = a;
}

// ================= fc3 + sigmoid =================
__global__ __launch_bounds__(256) void fc3_kernel(
    const float* __restrict__ f2g, const float* __restrict__ fc3_w,
    const float* __restrict__ fc3_b, float* __restrict__ out) {
  int b = blockIdx.x >> 2;
  int oc = (blockIdx.x & 3) * 196;
  __shared__ float f2[1024];
  for (int l = threadIdx.x; l < 1024; l += 256) f2[l] = f2g[b * 1024 + l];
  __syncthreads();
  if (threadIdx.x >= 196) return;
  int o = oc + threadIdx.x;
  const float4* wr = reinterpret_cast<const float4*>(&fc3_w[o * 1024]);
  float a = fc3_b[o];
#pragma unroll 4
  for (int k4 = 0; k4 < 256; ++k4) {
    float4 w4 = wr[k4];
    a += f2[4 * k4] * w4.x + f2[4 * k4 + 1] * w4.y + f2[4 * k4 + 2] * w4.z +
         f2[4 * k4 + 3] * w4.w;
  }
  out[1280 + b * 784 + o] = 1.f / (1.f + __expf(-a));
}

extern "C" void kernel_launch(void* const* d_in, const int* in_sizes, int n_in,
                              void* d_out, int out_size, void* d_ws, size_t ws_size,
                              hipStream_t stream) {
  const float* x       = (const float*)d_in[0];
  const float* y       = (const float*)d_in[1];
  const float* conv1_w = (const float*)d_in[2];
  const float* conv1_b = (const float*)d_in[3];
  const float* caps1_w = (const float*)d_in[4];
  const float* caps1_b = (const float*)d_in[5];
  const float* W       = (const float*)d_in[6];
  const float* cbias   = (const float*)d_in[7];
  const float* fc1_w   = (const float*)d_in[8];
  const float* fc1_b   = (const float*)d_in[9];
  const float* fc2_w   = (const float*)d_in[10];
  const float* fc2_b   = (const float*)d_in[11];
  const float* fc3_w   = (const float*)d_in[12];
  const float* fc3_b   = (const float*)d_in[13];
  float* out = (float*)d_out;

  char* wsb = (char*)d_ws;
  ushort_t* h1t  = (ushort_t*)(wsb + OFFB_H1T);
  ushort_t* wt   = (ushort_t*)(wsb + OFFB_WT);
  float*    part = (float*)(wsb + OFFB_PART);
  float*    h2   = (float*)(wsb + OFFB_H2);
  ushort_t* uh   = (ushort_t*)(wsb + OFFB_UH);
  float*    bij  = (float*)(wsb + OFFB_BIJ);
  float*    c    = (float*)(wsb + OFFB_C);
  float*    v    = (float*)(wsb + OFFB_V);
  float*    f1   = (float*)(wsb + OFFB_F1);
  float*    f2   = (float*)(wsb + OFFB_F2);

  conv1_kernel<<<2560, 256, 0, stream>>>(x, conv1_w, conv1_b, h1t);
  wreorder_kernel<<<256, 256, 0, stream>>>(caps1_w, wt);
  caps1_gemm<<<1152, 256, 0, stream>>>(h1t, wt, part);
  reduce_kernel<<<4608, 256, 0, stream>>>(part, caps1_b, h2);
  uhat_kernel<<<1440, 256, 0, stream>>>(h2, W, uh);

  sv_kernel<0><<<1280, 64, 0, stream>>>(uh, c, cbias, v, out);
  agree_kernel<true><<<576, 256, 0, stream>>>(uh, v, bij, c);
  sv_kernel<1><<<1280, 64, 0, stream>>>(uh, c, cbias, v, out);
  agree_kernel<false><<<576, 256, 0, stream>>>(uh, v, bij, c);
  sv_kernel<2><<<1280, 64, 0, stream>>>(uh, c, cbias, v, out);

  fc1_kernel<<<128, 128, 0, stream>>>(v, y, fc1_w, fc1_b, f1);
  fc2_kernel<<<512, 256, 0, stream>>>(f1, fc2_w, fc2_b, f2);
  fc3_kernel<<<512, 256, 0, stream>>>(f2, fc3_w, fc3_b, out);
}